// Round 13
// baseline (273.483 us; speedup 1.0000x reference)
//
#include <hip/hip_runtime.h>
#include <math.h>

#define BB 2048
#define LL 64
#define EE 200
#define HH 128
#define CDIM 128
#define VV 50000
#define G3 384    // 3H
#define PEW 768   // 2*3H
#define D2H 256   // 2H
#define EPSV 1e-5f

typedef __attribute__((ext_vector_type(8))) short short8v;
typedef __attribute__((ext_vector_type(4))) float f32x4;

__device__ __forceinline__ float fast_sigmoid(float v) {
    return __builtin_amdgcn_rcpf(1.f + __expf(-v));
}
__device__ __forceinline__ float fast_tanh(float a) {
    float e = __expf(-2.f * fabsf(a));
    float m = (1.f - e) * __builtin_amdgcn_rcpf(1.f + e);
    return copysignf(m, a);
}

// ---- bf16 (raw ushort) <-> f32 helpers; storage-dtype overloads ----
__device__ __forceinline__ float bf2f(unsigned short u) {
    union { unsigned int i; float f; } c; c.i = ((unsigned int)u) << 16; return c.f;
}
__device__ __forceinline__ unsigned short f2bf(float f) {
    union { float f; unsigned int i; } c; c.f = f;
    unsigned int r = c.i + 0x7FFF + ((c.i >> 16) & 1);   // round-nearest-even
    return (unsigned short)(r >> 16);
}
__device__ __forceinline__ float ldc(const float* p) { return *p; }
__device__ __forceinline__ float ldc(const unsigned short* p) { return bf2f(*p); }
__device__ __forceinline__ void stc(float* p, float v) { *p = v; }
__device__ __forceinline__ void stc(unsigned short* p, float v) { *p = f2bf(v); }
__device__ __forceinline__ float4 ld4(const float* p) { return *(const float4*)p; }
__device__ __forceinline__ float4 ld4(const unsigned short* p) {
    ushort4 u = *(const ushort4*)p;
    return make_float4(bf2f(u.x), bf2f(u.y), bf2f(u.z), bf2f(u.w));
}

// ---------------- K0: zero the BN stats accumulators ----------------
__global__ void zero_stats_kernel(float* __restrict__ stats) {
    if (threadIdx.x < 2 * LL) stats[threadIdx.x] = 0.f;
}

// ---------------- K1: projected-embedding table (fp32, Plan A) ------
template <typename T>
__global__ __launch_bounds__(256) void pe_kernel(
    const float* __restrict__ emb,
    const float* __restrict__ Wih_f, const float* __restrict__ bih_f,
    const float* __restrict__ Wih_b, const float* __restrict__ bih_b,
    T* __restrict__ PE)
{
    __shared__ float As[8][136];
    __shared__ float Bs[8][136];
    const int mb = blockIdx.x * 128;
    const int nb = blockIdx.y * 128;
    const float* W  = (nb < G3) ? Wih_f : Wih_b;
    const float* bi = (nb < G3) ? bih_f : bih_b;
    const int nloc  = (nb < G3) ? nb : nb - G3;
    const int t  = threadIdx.x;
    const int tr = t >> 4, tc = t & 15;
    const int r  = t >> 1, q = t & 1;
    float acc[8][8] = {};
    for (int k0 = 0; k0 < EE; k0 += 8) {
        float4 av, bv;
        const int arow = mb + r;
        if (arow < VV) av = *(const float4*)(emb + (size_t)arow * EE + k0 + q * 4);
        else           av = make_float4(0.f, 0.f, 0.f, 0.f);
        bv = *(const float4*)(W + (size_t)(nloc + r) * EE + k0 + q * 4);
        __syncthreads();
        #pragma unroll
        for (int m = 0; m < 4; ++m) {
            As[q * 4 + m][r] = (&av.x)[m];
            Bs[q * 4 + m][r] = (&bv.x)[m];
        }
        __syncthreads();
        #pragma unroll
        for (int k = 0; k < 8; ++k) {
            float4 a0 = *(const float4*)&As[k][tr * 4];
            float4 a1 = *(const float4*)&As[k][64 + tr * 4];
            float4 b0 = *(const float4*)&Bs[k][tc * 4];
            float4 b1 = *(const float4*)&Bs[k][64 + tc * 4];
            float a8[8] = {a0.x,a0.y,a0.z,a0.w,a1.x,a1.y,a1.z,a1.w};
            float b8[8] = {b0.x,b0.y,b0.z,b0.w,b1.x,b1.y,b1.z,b1.w};
            #pragma unroll
            for (int i = 0; i < 8; ++i)
                #pragma unroll
                for (int j = 0; j < 8; ++j)
                    acc[i][j] = fmaf(a8[i], b8[j], acc[i][j]);
        }
    }
    #pragma unroll
    for (int i = 0; i < 8; ++i) {
        const int rl  = (i < 4) ? (tr * 4 + i) : (64 + tr * 4 + i - 4);
        const int row = mb + rl;
        if (row >= VV) continue;
        #pragma unroll
        for (int j = 0; j < 8; ++j) {
            const int cl = (j < 4) ? (tc * 4 + j) : (64 + tc * 4 + j - 4);
            stc(&PE[(size_t)row * PEW + nb + cl], acc[i][j] + bi[nloc + cl]);
        }
    }
}

// ---------------- K1b: k-major float4 repack of a [R][K] matrix -----
__global__ void transpose4_kernel(const float* __restrict__ src,
                                  float* __restrict__ dst, int R, int K) {
    int idx = blockIdx.x * blockDim.x + threadIdx.x;
    int total = R * (K >> 2);
    if (idx >= total) return;
    int k4 = idx / R, r = idx - k4 * R;
    float4 v;
    v.x = src[r * K + k4 * 4 + 0];
    v.y = src[r * K + k4 * 4 + 1];
    v.z = src[r * K + k4 * 4 + 2];
    v.w = src[r * K + k4 * 4 + 3];
    ((float4*)dst)[idx] = v;
}

// ---------------- K1c: pack Whh into MFMA B-fragments (bf16 hi/lo) --
__global__ __launch_bounds__(64) void pack_whh_kernel(
    const float* __restrict__ Whh_f, const float* __restrict__ Whh_b,
    unsigned short* __restrict__ Wpk)
{
    const int fid = blockIdx.x;
    const int l   = threadIdx.x;
    const int g   = fid % 3;
    const int kt  = (fid / 3) & 3;
    const int p   = (fid / 12) & 1;
    const int w   = (fid / 24) & 7;
    const int dir = fid / 192;
    const float* W = dir ? Whh_b : Whh_f;
    const int n  = g * HH + w * 16 + (l & 15);
    const int k0 = kt * 32 + (l >> 4) * 8;
    unsigned short* dst = Wpk + (size_t)fid * 512 + l * 8;
    #pragma unroll
    for (int r = 0; r < 8; ++r) {
        float v = W[(size_t)n * HH + k0 + r];
        unsigned short hi = f2bf(v);
        dst[r] = p ? f2bf(v - bf2f(hi)) : hi;
    }
}

// ---------------- K1d: pack Wp into MFMA B-fragments (bf16 hi/lo) ---
__global__ __launch_bounds__(64) void pack_wp_kernel(
    const float* __restrict__ Wp, unsigned short* __restrict__ WpPk)
{
    const int fid = blockIdx.x;
    const int l   = threadIdx.x;
    const int nt  = fid & 7;
    const int kt  = (fid >> 3) & 7;
    const int p   = fid >> 6;
    const int n   = nt * 16 + (l & 15);
    const int k0  = kt * 32 + (l >> 4) * 8;
    unsigned short* dst = WpPk + (size_t)fid * 512 + l * 8;
    #pragma unroll
    for (int r = 0; r < 8; ++r) {
        float v = Wp[(size_t)n * D2H + k0 + r];
        unsigned short hi = f2bf(v);
        dst[r] = p ? f2bf(v - bf2f(hi)) : hi;
    }
}

// ---------------- K1e: pack Wih into MFMA B-fragments (bf16 hi/lo) --
__global__ __launch_bounds__(64) void pack_wih_kernel(
    const float* __restrict__ Wih_f, const float* __restrict__ Wih_b,
    unsigned short* __restrict__ WihPk)
{
    const int fid = blockIdx.x;
    const int l   = threadIdx.x;
    const int nt  = fid % 48;
    const int kt  = (fid / 48) % 7;
    const int p   = fid / 336;
    const int n   = nt * 16 + (l & 15);
    const int k0  = kt * 32 + (l >> 4) * 8;
    const float* W = (n < G3) ? Wih_f : Wih_b;
    const int nl   = (n < G3) ? n : n - G3;
    unsigned short* dst = WihPk + (size_t)fid * 512 + l * 8;
    #pragma unroll
    for (int r = 0; r < 8; ++r) {
        const int k = k0 + r;
        float v = (k < EE) ? W[(size_t)nl * EE + k] : 0.f;
        unsigned short hi = f2bf(v);
        dst[r] = p ? f2bf(v - bf2f(hi)) : hi;
    }
}

// ---------------- K1': PE table via MFMA (Plan C) -------------------
// 1563 blocks x 512 threads (8 waves). Stage 32 emb rows ONCE (fetch ~27MB),
// 3 iterations x (8 waves x 2 n-tiles) cover all 48 n-tiles.
__global__ __launch_bounds__(512) void pe_mfma_kernel(
    const float* __restrict__ emb,
    const unsigned short* __restrict__ WihPk,
    const float* __restrict__ bih_f, const float* __restrict__ bih_b,
    unsigned short* __restrict__ PE)
{
    __shared__ unsigned short ahi[32][264];
    __shared__ unsigned short alo[32][264];
    const int b0 = blockIdx.x * 32;
    const int t  = threadIdx.x;
    const int w  = t >> 6, ln = t & 63;     // 8 waves
    for (int idx = t; idx < 32 * 56; idx += 512) {
        const int r = idx / 56, q = idx - r * 56;
        const int row = b0 + r;
        float4 v = make_float4(0.f, 0.f, 0.f, 0.f);
        if (row < VV && q < 50)
            v = *(const float4*)(emb + (size_t)row * EE + q * 4);
        ushort4 h4, l4;
        #pragma unroll
        for (int m = 0; m < 4; ++m) {
            const float f = (&v.x)[m];
            const unsigned short hi = f2bf(f);
            (&h4.x)[m] = hi;
            (&l4.x)[m] = f2bf(f - bf2f(hi));
        }
        *(ushort4*)&ahi[r][q * 4] = h4;
        *(ushort4*)&alo[r][q * 4] = l4;
    }
    __syncthreads();
    const int sa = ln & 15, ka = (ln >> 4) * 8;
    const int rb = (ln >> 4) * 4;
    #pragma unroll
    for (int it = 0; it < 3; ++it) {
        const int ntb = it * 16 + w * 2;    // this wave's first n-tile (0..47)
        f32x4 acc00 = {0.f,0.f,0.f,0.f}, acc01 = {0.f,0.f,0.f,0.f};
        f32x4 acc10 = {0.f,0.f,0.f,0.f}, acc11 = {0.f,0.f,0.f,0.f};
        #pragma unroll
        for (int kt = 0; kt < 7; ++kt) {
            short8v ah0 = *(const short8v*)&ahi[sa][kt * 32 + ka];
            short8v ah1 = *(const short8v*)&ahi[16 + sa][kt * 32 + ka];
            short8v al0 = *(const short8v*)&alo[sa][kt * 32 + ka];
            short8v al1 = *(const short8v*)&alo[16 + sa][kt * 32 + ka];
            const unsigned short* bb = WihPk + ((size_t)(kt * 48 + ntb)) * 512 + (size_t)ln * 8;
            short8v bh0 = *(const short8v*)(bb);
            short8v bh1 = *(const short8v*)(bb + 512);
            short8v bl0 = *(const short8v*)(bb + (size_t)336 * 512);
            short8v bl1 = *(const short8v*)(bb + (size_t)336 * 512 + 512);
            acc00 = __builtin_amdgcn_mfma_f32_16x16x32_bf16(ah0, bh0, acc00, 0, 0, 0);
            acc00 = __builtin_amdgcn_mfma_f32_16x16x32_bf16(ah0, bl0, acc00, 0, 0, 0);
            acc00 = __builtin_amdgcn_mfma_f32_16x16x32_bf16(al0, bh0, acc00, 0, 0, 0);
            acc01 = __builtin_amdgcn_mfma_f32_16x16x32_bf16(ah0, bh1, acc01, 0, 0, 0);
            acc01 = __builtin_amdgcn_mfma_f32_16x16x32_bf16(ah0, bl1, acc01, 0, 0, 0);
            acc01 = __builtin_amdgcn_mfma_f32_16x16x32_bf16(al0, bh1, acc01, 0, 0, 0);
            acc10 = __builtin_amdgcn_mfma_f32_16x16x32_bf16(ah1, bh0, acc10, 0, 0, 0);
            acc10 = __builtin_amdgcn_mfma_f32_16x16x32_bf16(ah1, bl0, acc10, 0, 0, 0);
            acc10 = __builtin_amdgcn_mfma_f32_16x16x32_bf16(al1, bh0, acc10, 0, 0, 0);
            acc11 = __builtin_amdgcn_mfma_f32_16x16x32_bf16(ah1, bh1, acc11, 0, 0, 0);
            acc11 = __builtin_amdgcn_mfma_f32_16x16x32_bf16(ah1, bl1, acc11, 0, 0, 0);
            acc11 = __builtin_amdgcn_mfma_f32_16x16x32_bf16(al1, bh1, acc11, 0, 0, 0);
        }
        #pragma unroll
        for (int n2 = 0; n2 < 2; ++n2) {
            const int col = (ntb + n2) * 16 + (ln & 15);
            const float bias = (col < G3) ? bih_f[col] : bih_b[col - G3];
            #pragma unroll
            for (int mt = 0; mt < 2; ++mt) {
                const f32x4 a = mt == 0 ? (n2 == 0 ? acc00 : acc01)
                                        : (n2 == 0 ? acc10 : acc11);
                #pragma unroll
                for (int reg = 0; reg < 4; ++reg) {
                    const int row = b0 + mt * 16 + rb + reg;
                    if (row < VV)
                        stc(&PE[(size_t)row * PEW + col], a[reg] + bias);
                }
            }
        }
    }
}

// ---------------- K2: bidirectional GRU recurrence (MFMA, pipelined) -
// r13 change: per-step barrier is raw s_barrier with lgkmcnt-only drain.
// __syncthreads() emits s_waitcnt vmcnt(0) before s_barrier, which drained
// the x(t+1) prefetch loads AND the out stores every step. Only the h LDS
// double-buffer needs inter-wave ordering -> lgkmcnt(0) suffices.
template <typename TPE, typename TOUT>
__global__ __launch_bounds__(512, 2) void gru_kernel(
    const int* __restrict__ xw, const int* __restrict__ lens,
    const TPE* __restrict__ PE,
    const unsigned short* __restrict__ Wpk,
    const float* __restrict__ bhh_f, const float* __restrict__ bhh_b,
    TOUT* __restrict__ out)
{
    const int dir = blockIdx.x >> 7;
    const int b0  = (blockIdx.x & 127) * 16;
    const float* bhh = dir ? bhh_b : bhh_f;
    const int t = threadIdx.x;
    const int w = t >> 6;
    const int l = t & 63;
    const int j  = w * 16 + (l & 15);
    const int sb = (l >> 4) * 4;
    const int sa = l & 15;
    const int ka = (l >> 4) * 8;
    __shared__ unsigned short hhi[2][16][136];
    __shared__ unsigned short hlo[2][16][136];

    short8v wb[2][4][3];
    #pragma unroll
    for (int p = 0; p < 2; ++p)
        #pragma unroll
        for (int kt = 0; kt < 4; ++kt)
            #pragma unroll
            for (int g = 0; g < 3; ++g) {
                const size_t fid = (size_t)(dir * 192 + w * 24 + p * 12 + kt * 3 + g);
                wb[p][kt][g] = *(const short8v*)(Wpk + fid * 512 + (size_t)l * 8);
            }
    for (int i = t; i < 16 * 136; i += 512) {
        ((unsigned short*)hhi[0])[i] = 0;
        ((unsigned short*)hlo[0])[i] = 0;
    }
    const float br  = bhh[j], bz = bhh[HH + j], bn_ = bhh[2 * HH + j];
    int lens_r[4];
    #pragma unroll
    for (int r = 0; r < 4; ++r) lens_r[r] = lens[b0 + sb + r];
    const int peBase = dir * G3;
    float hprev[4] = {0.f, 0.f, 0.f, 0.f};
    float xr[4], xz[4], xn[4];
    {
        const int lseq = dir ? (LL - 1) : 0;
        #pragma unroll
        for (int r = 0; r < 4; ++r) {
            const int tok = xw[(b0 + sb + r) * LL + lseq];
            const TPE* pp = PE + (size_t)tok * PEW + peBase + j;
            xr[r] = ldc(pp); xz[r] = ldc(pp + HH); xn[r] = ldc(pp + 2 * HH);
        }
    }
    __syncthreads();

    for (int step = 0; step < LL; ++step) {
        const int cur = step & 1, nxt = cur ^ 1;
        const int lseq = dir ? (LL - 1 - step) : step;
        short8v ah[4], al[4];
        #pragma unroll
        for (int kt = 0; kt < 4; ++kt) {
            ah[kt] = *(const short8v*)&hhi[cur][sa][kt * 32 + ka];
            al[kt] = *(const short8v*)&hlo[cur][sa][kt * 32 + ka];
        }
        float xrn[4], xzn[4], xnn[4];
        if (step < LL - 1) {
            const int lq = dir ? (LL - 2 - step) : (step + 1);
            #pragma unroll
            for (int r = 0; r < 4; ++r) {
                const int tok = xw[(b0 + sb + r) * LL + lq];
                const TPE* pp = PE + (size_t)tok * PEW + peBase + j;
                xrn[r] = ldc(pp); xzn[r] = ldc(pp + HH); xnn[r] = ldc(pp + 2 * HH);
            }
        }
        f32x4 aR = {0.f,0.f,0.f,0.f}, aZ = {0.f,0.f,0.f,0.f}, aN = {0.f,0.f,0.f,0.f};
        #pragma unroll
        for (int kt = 0; kt < 4; ++kt) {
            aR = __builtin_amdgcn_mfma_f32_16x16x32_bf16(ah[kt], wb[0][kt][0], aR, 0, 0, 0);
            aZ = __builtin_amdgcn_mfma_f32_16x16x32_bf16(ah[kt], wb[0][kt][1], aZ, 0, 0, 0);
            aN = __builtin_amdgcn_mfma_f32_16x16x32_bf16(ah[kt], wb[0][kt][2], aN, 0, 0, 0);
            aR = __builtin_amdgcn_mfma_f32_16x16x32_bf16(ah[kt], wb[1][kt][0], aR, 0, 0, 0);
            aZ = __builtin_amdgcn_mfma_f32_16x16x32_bf16(ah[kt], wb[1][kt][1], aZ, 0, 0, 0);
            aN = __builtin_amdgcn_mfma_f32_16x16x32_bf16(ah[kt], wb[1][kt][2], aN, 0, 0, 0);
            aR = __builtin_amdgcn_mfma_f32_16x16x32_bf16(al[kt], wb[0][kt][0], aR, 0, 0, 0);
            aZ = __builtin_amdgcn_mfma_f32_16x16x32_bf16(al[kt], wb[0][kt][1], aZ, 0, 0, 0);
            aN = __builtin_amdgcn_mfma_f32_16x16x32_bf16(al[kt], wb[0][kt][2], aN, 0, 0, 0);
        }
        #pragma unroll
        for (int r = 0; r < 4; ++r) {
            const int s = sb + r;
            const float rr = fast_sigmoid(xr[r] + aR[r] + br);
            const float zz = fast_sigmoid(xz[r] + aZ[r] + bz);
            const float nn = fast_tanh(xn[r] + rr * (aN[r] + bn_));
            const float h  = (1.f - zz) * nn + zz * hprev[r];
            hprev[r] = h;
            const unsigned short hi = f2bf(h);
            hhi[nxt][s][j] = hi;
            hlo[nxt][s][j] = f2bf(h - bf2f(hi));
            stc(&out[((size_t)(b0 + s) * LL + lseq) * D2H + dir * HH + j],
                (lseq < lens_r[r]) ? h : 0.f);
        }
        if (step < LL - 1) {
            #pragma unroll
            for (int r = 0; r < 4; ++r) {
                xr[r] = xrn[r]; xz[r] = xzn[r]; xn[r] = xnn[r];
            }
        }
        // raw barrier: drain LDS ops only; stores/prefetch stay in flight
        __builtin_amdgcn_sched_barrier(0);
        asm volatile("s_waitcnt lgkmcnt(0)" ::: "memory");
        __builtin_amdgcn_s_barrier();
        __builtin_amdgcn_sched_barrier(0);
    }
}

// ---------------- K3: projection GEMM + BN stats (fp32, Plan A) -----
template <typename TOUT>
__global__ __launch_bounds__(256) void proj_kernel(
    const TOUT* __restrict__ out, const float* __restrict__ WpT4,
    const float* __restrict__ bp,
    float* __restrict__ proj, float* __restrict__ stats)
{
    __shared__ float outs[32][D2H];
    __shared__ float red[2][4];
    const int b0 = blockIdx.x * 32;
    const int l  = blockIdx.y;
    const int t  = threadIdx.x;
    for (int idx = t; idx < 32 * (D2H / 4); idx += 256) {
        int r = idx >> 6, c4 = idx & 63;
        float4 v = ld4(out + ((size_t)(b0 + r) * LL + l) * D2H + c4 * 4);
        *((float4*)&outs[r][c4 * 4]) = v;
    }
    __syncthreads();
    const int tr = t >> 5;
    const int tc = t & 31;
    float acc[4][4] = {};
    for (int k4 = 0; k4 < D2H / 4; ++k4) {
        float4 w[4];
        #pragma unroll
        for (int jj = 0; jj < 4; ++jj)
            w[jj] = ((const float4*)WpT4)[k4 * CDIM + tc * 4 + jj];
        #pragma unroll
        for (int i = 0; i < 4; ++i) {
            float4 a = *((const float4*)&outs[tr * 4 + i][k4 * 4]);
            #pragma unroll
            for (int jj = 0; jj < 4; ++jj) {
                acc[i][jj] = fmaf(a.x, w[jj].x, acc[i][jj]);
                acc[i][jj] = fmaf(a.y, w[jj].y, acc[i][jj]);
                acc[i][jj] = fmaf(a.z, w[jj].z, acc[i][jj]);
                acc[i][jj] = fmaf(a.w, w[jj].w, acc[i][jj]);
            }
        }
    }
    float s1 = 0.f, s2 = 0.f;
    #pragma unroll
    for (int i = 0; i < 4; ++i) {
        int b = b0 + tr * 4 + i;
        float4 pv;
        #pragma unroll
        for (int jj = 0; jj < 4; ++jj) {
            float v = acc[i][jj] + bp[tc * 4 + jj];
            (&pv.x)[jj] = v;
            s1 += v; s2 += v * v;
        }
        *((float4*)(proj + ((size_t)b * LL + l) * CDIM + tc * 4)) = pv;
    }
    #pragma unroll
    for (int off = 32; off > 0; off >>= 1) {
        s1 += __shfl_down(s1, off);
        s2 += __shfl_down(s2, off);
    }
    const int lane = t & 63, wv = t >> 6;
    if (lane == 0) { red[0][wv] = s1; red[1][wv] = s2; }
    __syncthreads();
    if (t == 0) {
        atomicAdd(&stats[l],      red[0][0] + red[0][1] + red[0][2] + red[0][3]);
        atomicAdd(&stats[LL + l], red[1][0] + red[1][1] + red[1][2] + red[1][3]);
    }
}

// ---------------- K3': projection via MFMA (bf16 out) + BN stats ----
__global__ __launch_bounds__(256) void proj_mfma_kernel(
    const unsigned short* __restrict__ out, const unsigned short* __restrict__ WpPk,
    const float* __restrict__ bp,
    float* __restrict__ proj, float* __restrict__ stats)
{
    __shared__ unsigned short outs[32][264];
    __shared__ float red[2][4];
    const int b0 = blockIdx.x * 32;
    const int l  = blockIdx.y;
    const int t  = threadIdx.x;
    const int w  = t >> 6, ln = t & 63;
    for (int idx = t; idx < 1024; idx += 256) {
        const int r = idx >> 5, c8 = idx & 31;
        *(short8v*)&outs[r][c8 * 8] =
            *(const short8v*)(out + ((size_t)(b0 + r) * LL + l) * D2H + c8 * 8);
    }
    __syncthreads();
    const int sa = ln & 15, ka = (ln >> 4) * 8;
    f32x4 acc00 = {0.f,0.f,0.f,0.f}, acc01 = {0.f,0.f,0.f,0.f};
    f32x4 acc10 = {0.f,0.f,0.f,0.f}, acc11 = {0.f,0.f,0.f,0.f};
    #pragma unroll
    for (int kt = 0; kt < 8; ++kt) {
        short8v a0 = *(const short8v*)&outs[sa][kt * 32 + ka];
        short8v a1 = *(const short8v*)&outs[16 + sa][kt * 32 + ka];
        const unsigned short* bbase = WpPk + ((size_t)kt * 8 + w * 2) * 512 + (size_t)ln * 8;
        short8v bh0 = *(const short8v*)(bbase);
        short8v bh1 = *(const short8v*)(bbase + 512);
        short8v bl0 = *(const short8v*)(bbase + 64 * 512);
        short8v bl1 = *(const short8v*)(bbase + 64 * 512 + 512);
        acc00 = __builtin_amdgcn_mfma_f32_16x16x32_bf16(a0, bh0, acc00, 0, 0, 0);
        acc00 = __builtin_amdgcn_mfma_f32_16x16x32_bf16(a0, bl0, acc00, 0, 0, 0);
        acc01 = __builtin_amdgcn_mfma_f32_16x16x32_bf16(a0, bh1, acc01, 0, 0, 0);
        acc01 = __builtin_amdgcn_mfma_f32_16x16x32_bf16(a0, bl1, acc01, 0, 0, 0);
        acc10 = __builtin_amdgcn_mfma_f32_16x16x32_bf16(a1, bh0, acc10, 0, 0, 0);
        acc10 = __builtin_amdgcn_mfma_f32_16x16x32_bf16(a1, bl0, acc10, 0, 0, 0);
        acc11 = __builtin_amdgcn_mfma_f32_16x16x32_bf16(a1, bh1, acc11, 0, 0, 0);
        acc11 = __builtin_amdgcn_mfma_f32_16x16x32_bf16(a1, bl1, acc11, 0, 0, 0);
    }
    float s1 = 0.f, s2 = 0.f;
    const int rb = (ln >> 4) * 4;
    const int cb = w * 32 + (ln & 15);
    #pragma unroll
    for (int mt = 0; mt < 2; ++mt) {
        #pragma unroll
        for (int n2 = 0; n2 < 2; ++n2) {
            const f32x4 a = mt == 0 ? (n2 == 0 ? acc00 : acc01)
                                    : (n2 == 0 ? acc10 : acc11);
            const int col = cb + n2 * 16;
            const float bpv = bp[col];
            #pragma unroll
            for (int reg = 0; reg < 4; ++reg) {
                const int row = b0 + mt * 16 + rb + reg;
                const float v = a[reg] + bpv;
                proj[((size_t)row * LL + l) * CDIM + col] = v;
                s1 += v; s2 += v * v;
            }
        }
    }
    #pragma unroll
    for (int off = 32; off > 0; off >>= 1) {
        s1 += __shfl_down(s1, off);
        s2 += __shfl_down(s2, off);
    }
    if (ln == 0) { red[0][w] = s1; red[1][w] = s2; }
    __syncthreads();
    if (t == 0) {
        atomicAdd(&stats[l],      red[0][0] + red[0][1] + red[0][2] + red[0][3]);
        atomicAdd(&stats[LL + l], red[1][0] + red[1][1] + red[1][2] + red[1][3]);
    }
}

// ---------------- K4: BN apply + relu + dot with ctx ----------------
__global__ __launch_bounds__(256) void logits_kernel(
    const float* __restrict__ proj, const float* __restrict__ stats,
    const float* __restrict__ gamma, const float* __restrict__ beta,
    const float* __restrict__ ctx, float* __restrict__ logits)
{
    const int idx  = blockIdx.x * 4 + (threadIdx.x >> 6);
    const int lane = threadIdx.x & 63;
    const int b = idx >> 6, l = idx & 63;
    const float invN = 1.f / (float)(BB * CDIM);
    const float mean = stats[l] * invN;
    const float var  = stats[LL + l] * invN - mean * mean;
    const float inv  = rsqrtf(var + EPSV);
    const float g = gamma[l], be = beta[l];
    const float2 p = ((const float2*)(proj + ((size_t)b * LL + l) * CDIM))[lane];
    const float2 c = ((const float2*)ctx)[lane];
    float v0 = fmaxf((p.x - mean) * inv * g + be, 0.f);
    float v1 = fmaxf((p.y - mean) * inv * g + be, 0.f);
    float s = v0 * c.x + v1 * c.y;
    #pragma unroll
    for (int off = 32; off > 0; off >>= 1) s += __shfl_down(s, off);
    if (lane == 0) logits[idx] = s;
}

// ---------------- K5: softmax over L + weighted sum -----------------
template <typename TOUT>
__global__ __launch_bounds__(256) void att_out_kernel(
    const TOUT* __restrict__ out, const float* __restrict__ logits,
    float* __restrict__ y)
{
    const int b = blockIdx.x;
    const int t = threadIdx.x;
    __shared__ float att[LL];
    if (t < 64) {
        float v = logits[b * LL + t];
        float m = v;
        #pragma unroll
        for (int off = 32; off > 0; off >>= 1) m = fmaxf(m, __shfl_xor(m, off));
        float e = __expf(v - m);
        float ssum = e;
        #pragma unroll
        for (int off = 32; off > 0; off >>= 1) ssum += __shfl_xor(ssum, off);
        att[t] = e / ssum;
    }
    __syncthreads();
    float acc = 0.f;
    const TOUT* ob = out + (size_t)b * LL * D2H + t;
    #pragma unroll
    for (int l = 0; l < LL; ++l) acc = fmaf(ldc(ob + (size_t)l * D2H), att[l], acc);
    y[b * D2H + t] = acc;
}

extern "C" void kernel_launch(void* const* d_in, const int* in_sizes, int n_in,
                              void* d_out, int out_size, void* d_ws, size_t ws_size,
                              hipStream_t stream) {
    const int*   xw     = (const int*)d_in[0];
    const int*   lens   = (const int*)d_in[2];
    const float* emb    = (const float*)d_in[3];
    const float* Wih_f  = (const float*)d_in[4];
    const float* Whh_f  = (const float*)d_in[5];
    const float* bih_f  = (const float*)d_in[6];
    const float* bhh_f  = (const float*)d_in[7];
    const float* Wih_b  = (const float*)d_in[8];
    const float* Whh_b  = (const float*)d_in[9];
    const float* bih_b  = (const float*)d_in[10];
    const float* bhh_b  = (const float*)d_in[11];
    const float* Wp     = (const float*)d_in[12];
    const float* bp     = (const float*)d_in[13];
    const float* gamma  = (const float*)d_in[14];
    const float* beta   = (const float*)d_in[15];
    const float* ctx    = (const float*)d_in[16];
    float* y = (float*)d_out;

    char* base = (char*)d_ws;
    size_t off = 0;
    auto alloc = [&](size_t bytes) -> void* {
        void* p = base + off; off += (bytes + 255) & ~(size_t)255; return p;
    };
    float* WpT4  = (float*)alloc((size_t)CDIM * D2H * 4);
    float* stats = (float*)alloc(2 * LL * 4);
    float* logit = (float*)alloc((size_t)BB * LL * 4);
    unsigned short* Wpk   = (unsigned short*)alloc((size_t)384 * 512 * 2);  // Whh frags
    unsigned short* WpPk  = (unsigned short*)alloc((size_t)128 * 512 * 2);  // Wp frags
    unsigned short* WihPk = (unsigned short*)alloc((size_t)672 * 512 * 2);  // Wih frags
    const size_t extras = off;
    const size_t peB_A  = (size_t)VV * PEW * 4;
    const size_t outB_A = (size_t)BB * LL * D2H * 4;
    const size_t needA  = extras + peB_A + outB_A + 4096;
    const bool planA = ws_size >= needA;

    zero_stats_kernel<<<1, 128, 0, stream>>>(stats);
    pack_whh_kernel<<<384, 64, 0, stream>>>(Whh_f, Whh_b, Wpk);

    if (planA) {
        transpose4_kernel<<<(CDIM * D2H / 4 + 255) / 256, 256, 0, stream>>>(Wp, WpT4, CDIM, D2H);
        float* PE   = (float*)alloc(peB_A);
        float* outb = (float*)alloc(outB_A);
        float* proj = (float*)PE;   // alias: PE dead after gru_kernel
        pe_kernel<float><<<dim3((VV + 127) / 128, PEW / 128), 256, 0, stream>>>(
            emb, Wih_f, bih_f, Wih_b, bih_b, PE);
        gru_kernel<float, float><<<256, 512, 0, stream>>>(
            xw, lens, PE, Wpk, bhh_f, bhh_b, outb);
        proj_kernel<float><<<dim3(BB / 32, LL), 256, 0, stream>>>(outb, WpT4, bp, proj, stats);
        logits_kernel<<<BB * LL / 4, 256, 0, stream>>>(proj, stats, gamma, beta, ctx, logit);
        att_out_kernel<float><<<BB, 256, 0, stream>>>(outb, logit, y);
    } else {
        pack_wp_kernel<<<128, 64, 0, stream>>>(Wp, WpPk);
        pack_wih_kernel<<<672, 64, 0, stream>>>(Wih_f, Wih_b, WihPk);
        unsigned short* PE   = (unsigned short*)alloc((size_t)VV * PEW * 2);
        unsigned short* outb = (unsigned short*)alloc((size_t)BB * LL * D2H * 2);
        float* proj = (float*)PE;   // alias: 67MB fp32 <= 76.8MB bf16 PE region
        pe_mfma_kernel<<<(VV + 31) / 32, 512, 0, stream>>>(
            emb, WihPk, bih_f, bih_b, PE);
        gru_kernel<unsigned short, unsigned short><<<256, 512, 0, stream>>>(
            xw, lens, PE, Wpk, bhh_f, bhh_b, outb);
        proj_mfma_kernel<<<dim3(BB / 32, LL), 256, 0, stream>>>(outb, WpPk, bp, proj, stats);
        logits_kernel<<<BB * LL / 4, 256, 0, stream>>>(proj, stats, gamma, beta, ctx, logit);
        att_out_kernel<unsigned short><<<BB, 256, 0, stream>>>(outb, logit, y);
    }
}

// Round 14
// 249.609 us; speedup vs baseline: 1.0956x; 1.0956x over previous
//
#include <hip/hip_runtime.h>
#include <math.h>

#define BB 2048
#define LL 64
#define EE 200
#define HH 128
#define CDIM 128
#define VV 50000
#define G3 384    // 3H
#define PEW 768   // 2*3H
#define D2H 256   // 2H
#define EPSV 1e-5f

typedef __attribute__((ext_vector_type(8))) short short8v;
typedef __attribute__((ext_vector_type(4))) float f32x4;

__device__ __forceinline__ float fast_sigmoid(float v) {
    return __builtin_amdgcn_rcpf(1.f + __expf(-v));
}
__device__ __forceinline__ float fast_tanh(float a) {
    float e = __expf(-2.f * fabsf(a));
    float m = (1.f - e) * __builtin_amdgcn_rcpf(1.f + e);
    return copysignf(m, a);
}

// ---- bf16 (raw ushort) <-> f32 helpers; storage-dtype overloads ----
__device__ __forceinline__ float bf2f(unsigned short u) {
    union { unsigned int i; float f; } c; c.i = ((unsigned int)u) << 16; return c.f;
}
__device__ __forceinline__ unsigned short f2bf(float f) {
    union { float f; unsigned int i; } c; c.f = f;
    unsigned int r = c.i + 0x7FFF + ((c.i >> 16) & 1);   // round-nearest-even
    return (unsigned short)(r >> 16);
}
__device__ __forceinline__ float ldc(const float* p) { return *p; }
__device__ __forceinline__ float ldc(const unsigned short* p) { return bf2f(*p); }
__device__ __forceinline__ void stc(float* p, float v) { *p = v; }
__device__ __forceinline__ void stc(unsigned short* p, float v) { *p = f2bf(v); }
__device__ __forceinline__ float4 ld4(const float* p) { return *(const float4*)p; }
__device__ __forceinline__ float4 ld4(const unsigned short* p) {
    ushort4 u = *(const ushort4*)p;
    return make_float4(bf2f(u.x), bf2f(u.y), bf2f(u.z), bf2f(u.w));
}

// ---------------- K0: zero the BN stats accumulators ----------------
__global__ void zero_stats_kernel(float* __restrict__ stats) {
    if (threadIdx.x < 2 * LL) stats[threadIdx.x] = 0.f;
}

// ---------------- K1: projected-embedding table (fp32, Plan A) ------
template <typename T>
__global__ __launch_bounds__(256) void pe_kernel(
    const float* __restrict__ emb,
    const float* __restrict__ Wih_f, const float* __restrict__ bih_f,
    const float* __restrict__ Wih_b, const float* __restrict__ bih_b,
    T* __restrict__ PE)
{
    __shared__ float As[8][136];
    __shared__ float Bs[8][136];
    const int mb = blockIdx.x * 128;
    const int nb = blockIdx.y * 128;
    const float* W  = (nb < G3) ? Wih_f : Wih_b;
    const float* bi = (nb < G3) ? bih_f : bih_b;
    const int nloc  = (nb < G3) ? nb : nb - G3;
    const int t  = threadIdx.x;
    const int tr = t >> 4, tc = t & 15;
    const int r  = t >> 1, q = t & 1;
    float acc[8][8] = {};
    for (int k0 = 0; k0 < EE; k0 += 8) {
        float4 av, bv;
        const int arow = mb + r;
        if (arow < VV) av = *(const float4*)(emb + (size_t)arow * EE + k0 + q * 4);
        else           av = make_float4(0.f, 0.f, 0.f, 0.f);
        bv = *(const float4*)(W + (size_t)(nloc + r) * EE + k0 + q * 4);
        __syncthreads();
        #pragma unroll
        for (int m = 0; m < 4; ++m) {
            As[q * 4 + m][r] = (&av.x)[m];
            Bs[q * 4 + m][r] = (&bv.x)[m];
        }
        __syncthreads();
        #pragma unroll
        for (int k = 0; k < 8; ++k) {
            float4 a0 = *(const float4*)&As[k][tr * 4];
            float4 a1 = *(const float4*)&As[k][64 + tr * 4];
            float4 b0 = *(const float4*)&Bs[k][tc * 4];
            float4 b1 = *(const float4*)&Bs[k][64 + tc * 4];
            float a8[8] = {a0.x,a0.y,a0.z,a0.w,a1.x,a1.y,a1.z,a1.w};
            float b8[8] = {b0.x,b0.y,b0.z,b0.w,b1.x,b1.y,b1.z,b1.w};
            #pragma unroll
            for (int i = 0; i < 8; ++i)
                #pragma unroll
                for (int j = 0; j < 8; ++j)
                    acc[i][j] = fmaf(a8[i], b8[j], acc[i][j]);
        }
    }
    #pragma unroll
    for (int i = 0; i < 8; ++i) {
        const int rl  = (i < 4) ? (tr * 4 + i) : (64 + tr * 4 + i - 4);
        const int row = mb + rl;
        if (row >= VV) continue;
        #pragma unroll
        for (int j = 0; j < 8; ++j) {
            const int cl = (j < 4) ? (tc * 4 + j) : (64 + tc * 4 + j - 4);
            stc(&PE[(size_t)row * PEW + nb + cl], acc[i][j] + bi[nloc + cl]);
        }
    }
}

// ---------------- K1b: k-major float4 repack of a [R][K] matrix -----
__global__ void transpose4_kernel(const float* __restrict__ src,
                                  float* __restrict__ dst, int R, int K) {
    int idx = blockIdx.x * blockDim.x + threadIdx.x;
    int total = R * (K >> 2);
    if (idx >= total) return;
    int k4 = idx / R, r = idx - k4 * R;
    float4 v;
    v.x = src[r * K + k4 * 4 + 0];
    v.y = src[r * K + k4 * 4 + 1];
    v.z = src[r * K + k4 * 4 + 2];
    v.w = src[r * K + k4 * 4 + 3];
    ((float4*)dst)[idx] = v;
}

// ---------------- K1c: pack Whh into MFMA B-fragments (bf16 hi/lo) --
__global__ __launch_bounds__(64) void pack_whh_kernel(
    const float* __restrict__ Whh_f, const float* __restrict__ Whh_b,
    unsigned short* __restrict__ Wpk)
{
    const int fid = blockIdx.x;
    const int l   = threadIdx.x;
    const int g   = fid % 3;
    const int kt  = (fid / 3) & 3;
    const int p   = (fid / 12) & 1;
    const int w   = (fid / 24) & 7;
    const int dir = fid / 192;
    const float* W = dir ? Whh_b : Whh_f;
    const int n  = g * HH + w * 16 + (l & 15);
    const int k0 = kt * 32 + (l >> 4) * 8;
    unsigned short* dst = Wpk + (size_t)fid * 512 + l * 8;
    #pragma unroll
    for (int r = 0; r < 8; ++r) {
        float v = W[(size_t)n * HH + k0 + r];
        unsigned short hi = f2bf(v);
        dst[r] = p ? f2bf(v - bf2f(hi)) : hi;
    }
}

// ---------------- K1d: pack Wp into MFMA B-fragments (bf16 hi/lo) ---
__global__ __launch_bounds__(64) void pack_wp_kernel(
    const float* __restrict__ Wp, unsigned short* __restrict__ WpPk)
{
    const int fid = blockIdx.x;
    const int l   = threadIdx.x;
    const int nt  = fid & 7;
    const int kt  = (fid >> 3) & 7;
    const int p   = fid >> 6;
    const int n   = nt * 16 + (l & 15);
    const int k0  = kt * 32 + (l >> 4) * 8;
    unsigned short* dst = WpPk + (size_t)fid * 512 + l * 8;
    #pragma unroll
    for (int r = 0; r < 8; ++r) {
        float v = Wp[(size_t)n * D2H + k0 + r];
        unsigned short hi = f2bf(v);
        dst[r] = p ? f2bf(v - bf2f(hi)) : hi;
    }
}

// ---------------- K1e: pack Wih into MFMA B-fragments (bf16 hi/lo) --
__global__ __launch_bounds__(64) void pack_wih_kernel(
    const float* __restrict__ Wih_f, const float* __restrict__ Wih_b,
    unsigned short* __restrict__ WihPk)
{
    const int fid = blockIdx.x;
    const int l   = threadIdx.x;
    const int nt  = fid % 48;
    const int kt  = (fid / 48) % 7;
    const int p   = fid / 336;
    const int n   = nt * 16 + (l & 15);
    const int k0  = kt * 32 + (l >> 4) * 8;
    const float* W = (n < G3) ? Wih_f : Wih_b;
    const int nl   = (n < G3) ? n : n - G3;
    unsigned short* dst = WihPk + (size_t)fid * 512 + l * 8;
    #pragma unroll
    for (int r = 0; r < 8; ++r) {
        const int k = k0 + r;
        float v = (k < EE) ? W[(size_t)nl * EE + k] : 0.f;
        unsigned short hi = f2bf(v);
        dst[r] = p ? f2bf(v - bf2f(hi)) : hi;
    }
}

// ---------------- K1': PE table via MFMA (Plan C) -------------------
__global__ __launch_bounds__(512) void pe_mfma_kernel(
    const float* __restrict__ emb,
    const unsigned short* __restrict__ WihPk,
    const float* __restrict__ bih_f, const float* __restrict__ bih_b,
    unsigned short* __restrict__ PE)
{
    __shared__ unsigned short ahi[32][264];
    __shared__ unsigned short alo[32][264];
    const int b0 = blockIdx.x * 32;
    const int t  = threadIdx.x;
    const int w  = t >> 6, ln = t & 63;     // 8 waves
    for (int idx = t; idx < 32 * 56; idx += 512) {
        const int r = idx / 56, q = idx - r * 56;
        const int row = b0 + r;
        float4 v = make_float4(0.f, 0.f, 0.f, 0.f);
        if (row < VV && q < 50)
            v = *(const float4*)(emb + (size_t)row * EE + q * 4);
        ushort4 h4, l4;
        #pragma unroll
        for (int m = 0; m < 4; ++m) {
            const float f = (&v.x)[m];
            const unsigned short hi = f2bf(f);
            (&h4.x)[m] = hi;
            (&l4.x)[m] = f2bf(f - bf2f(hi));
        }
        *(ushort4*)&ahi[r][q * 4] = h4;
        *(ushort4*)&alo[r][q * 4] = l4;
    }
    __syncthreads();
    const int sa = ln & 15, ka = (ln >> 4) * 8;
    const int rb = (ln >> 4) * 4;
    #pragma unroll
    for (int it = 0; it < 3; ++it) {
        const int ntb = it * 16 + w * 2;    // this wave's first n-tile (0..47)
        f32x4 acc00 = {0.f,0.f,0.f,0.f}, acc01 = {0.f,0.f,0.f,0.f};
        f32x4 acc10 = {0.f,0.f,0.f,0.f}, acc11 = {0.f,0.f,0.f,0.f};
        #pragma unroll
        for (int kt = 0; kt < 7; ++kt) {
            short8v ah0 = *(const short8v*)&ahi[sa][kt * 32 + ka];
            short8v ah1 = *(const short8v*)&ahi[16 + sa][kt * 32 + ka];
            short8v al0 = *(const short8v*)&alo[sa][kt * 32 + ka];
            short8v al1 = *(const short8v*)&alo[16 + sa][kt * 32 + ka];
            const unsigned short* bb = WihPk + ((size_t)(kt * 48 + ntb)) * 512 + (size_t)ln * 8;
            short8v bh0 = *(const short8v*)(bb);
            short8v bh1 = *(const short8v*)(bb + 512);
            short8v bl0 = *(const short8v*)(bb + (size_t)336 * 512);
            short8v bl1 = *(const short8v*)(bb + (size_t)336 * 512 + 512);
            acc00 = __builtin_amdgcn_mfma_f32_16x16x32_bf16(ah0, bh0, acc00, 0, 0, 0);
            acc00 = __builtin_amdgcn_mfma_f32_16x16x32_bf16(ah0, bl0, acc00, 0, 0, 0);
            acc00 = __builtin_amdgcn_mfma_f32_16x16x32_bf16(al0, bh0, acc00, 0, 0, 0);
            acc01 = __builtin_amdgcn_mfma_f32_16x16x32_bf16(ah0, bh1, acc01, 0, 0, 0);
            acc01 = __builtin_amdgcn_mfma_f32_16x16x32_bf16(ah0, bl1, acc01, 0, 0, 0);
            acc01 = __builtin_amdgcn_mfma_f32_16x16x32_bf16(al0, bh1, acc01, 0, 0, 0);
            acc10 = __builtin_amdgcn_mfma_f32_16x16x32_bf16(ah1, bh0, acc10, 0, 0, 0);
            acc10 = __builtin_amdgcn_mfma_f32_16x16x32_bf16(ah1, bl0, acc10, 0, 0, 0);
            acc10 = __builtin_amdgcn_mfma_f32_16x16x32_bf16(al1, bh0, acc10, 0, 0, 0);
            acc11 = __builtin_amdgcn_mfma_f32_16x16x32_bf16(ah1, bh1, acc11, 0, 0, 0);
            acc11 = __builtin_amdgcn_mfma_f32_16x16x32_bf16(ah1, bl1, acc11, 0, 0, 0);
            acc11 = __builtin_amdgcn_mfma_f32_16x16x32_bf16(al1, bh1, acc11, 0, 0, 0);
        }
        #pragma unroll
        for (int n2 = 0; n2 < 2; ++n2) {
            const int col = (ntb + n2) * 16 + (ln & 15);
            const float bias = (col < G3) ? bih_f[col] : bih_b[col - G3];
            #pragma unroll
            for (int mt = 0; mt < 2; ++mt) {
                const f32x4 a = mt == 0 ? (n2 == 0 ? acc00 : acc01)
                                        : (n2 == 0 ? acc10 : acc11);
                #pragma unroll
                for (int reg = 0; reg < 4; ++reg) {
                    const int row = b0 + mt * 16 + rb + reg;
                    if (row < VV)
                        stc(&PE[(size_t)row * PEW + col], a[reg] + bias);
                }
            }
        }
    }
}

// ---------------- K2: bidirectional GRU recurrence (MFMA, pipelined) -
// r14 change: drop the h-lo path (issue diet). h stored bf16-only in LDS;
// W keeps hi/lo (register-resident, systematic error). Per thread-step:
// MFMA 36->24, ds_read 8->4, ds_write 8->4, lo-conversion VALU gone.
// Dropped terms (W*h_lo) contribute ~1e-4/step to preacts (<< 2^-9 floor).
template <typename TPE, typename TOUT>
__global__ __launch_bounds__(512, 2) void gru_kernel(
    const int* __restrict__ xw, const int* __restrict__ lens,
    const TPE* __restrict__ PE,
    const unsigned short* __restrict__ Wpk,
    const float* __restrict__ bhh_f, const float* __restrict__ bhh_b,
    TOUT* __restrict__ out)
{
    const int dir = blockIdx.x >> 7;
    const int b0  = (blockIdx.x & 127) * 16;
    const float* bhh = dir ? bhh_b : bhh_f;
    const int t = threadIdx.x;
    const int w = t >> 6;
    const int l = t & 63;
    const int j  = w * 16 + (l & 15);
    const int sb = (l >> 4) * 4;
    const int sa = l & 15;
    const int ka = (l >> 4) * 8;
    __shared__ unsigned short hh[2][16][136];

    short8v wb[2][4][3];
    #pragma unroll
    for (int p = 0; p < 2; ++p)
        #pragma unroll
        for (int kt = 0; kt < 4; ++kt)
            #pragma unroll
            for (int g = 0; g < 3; ++g) {
                const size_t fid = (size_t)(dir * 192 + w * 24 + p * 12 + kt * 3 + g);
                wb[p][kt][g] = *(const short8v*)(Wpk + fid * 512 + (size_t)l * 8);
            }
    for (int i = t; i < 16 * 136; i += 512)
        ((unsigned short*)hh[0])[i] = 0;
    const float br  = bhh[j], bz = bhh[HH + j], bn_ = bhh[2 * HH + j];
    int lens_r[4];
    #pragma unroll
    for (int r = 0; r < 4; ++r) lens_r[r] = lens[b0 + sb + r];
    const int peBase = dir * G3;
    float hprev[4] = {0.f, 0.f, 0.f, 0.f};
    float xr[4], xz[4], xn[4];
    {
        const int lseq = dir ? (LL - 1) : 0;
        #pragma unroll
        for (int r = 0; r < 4; ++r) {
            const int tok = xw[(b0 + sb + r) * LL + lseq];
            const TPE* pp = PE + (size_t)tok * PEW + peBase + j;
            xr[r] = ldc(pp); xz[r] = ldc(pp + HH); xn[r] = ldc(pp + 2 * HH);
        }
    }
    __syncthreads();

    for (int step = 0; step < LL; ++step) {
        const int cur = step & 1, nxt = cur ^ 1;
        const int lseq = dir ? (LL - 1 - step) : step;
        short8v ah[4];
        #pragma unroll
        for (int kt = 0; kt < 4; ++kt)
            ah[kt] = *(const short8v*)&hh[cur][sa][kt * 32 + ka];
        // unconditional clamped prefetch of x(step+1)
        float xrn[4], xzn[4], xnn[4];
        {
            int lq = dir ? (LL - 2 - step) : (step + 1);
            lq = lq < 0 ? 0 : (lq > LL - 1 ? LL - 1 : lq);
            #pragma unroll
            for (int r = 0; r < 4; ++r) {
                const int tok = xw[(b0 + sb + r) * LL + lq];
                const TPE* pp = PE + (size_t)tok * PEW + peBase + j;
                xrn[r] = ldc(pp); xzn[r] = ldc(pp + HH); xnn[r] = ldc(pp + 2 * HH);
            }
        }
        f32x4 aR = {0.f,0.f,0.f,0.f}, aZ = {0.f,0.f,0.f,0.f}, aN = {0.f,0.f,0.f,0.f};
        #pragma unroll
        for (int kt = 0; kt < 4; ++kt) {
            aR = __builtin_amdgcn_mfma_f32_16x16x32_bf16(ah[kt], wb[0][kt][0], aR, 0, 0, 0);
            aZ = __builtin_amdgcn_mfma_f32_16x16x32_bf16(ah[kt], wb[0][kt][1], aZ, 0, 0, 0);
            aN = __builtin_amdgcn_mfma_f32_16x16x32_bf16(ah[kt], wb[0][kt][2], aN, 0, 0, 0);
            aR = __builtin_amdgcn_mfma_f32_16x16x32_bf16(ah[kt], wb[1][kt][0], aR, 0, 0, 0);
            aZ = __builtin_amdgcn_mfma_f32_16x16x32_bf16(ah[kt], wb[1][kt][1], aZ, 0, 0, 0);
            aN = __builtin_amdgcn_mfma_f32_16x16x32_bf16(ah[kt], wb[1][kt][2], aN, 0, 0, 0);
        }
        #pragma unroll
        for (int r = 0; r < 4; ++r) {
            const int s = sb + r;
            const float rr = fast_sigmoid(xr[r] + aR[r] + br);
            const float zz = fast_sigmoid(xz[r] + aZ[r] + bz);
            const float nn = fast_tanh(xn[r] + rr * (aN[r] + bn_));
            const float h  = (1.f - zz) * nn + zz * hprev[r];
            hprev[r] = h;
            hh[nxt][s][j] = f2bf(h);
            stc(&out[((size_t)(b0 + s) * LL + lseq) * D2H + dir * HH + j],
                (lseq < lens_r[r]) ? h : 0.f);
        }
        #pragma unroll
        for (int r = 0; r < 4; ++r) {
            xr[r] = xrn[r]; xz[r] = xzn[r]; xn[r] = xnn[r];
        }
        // raw barrier: drain LDS ops only; stores/prefetch stay in flight
        __builtin_amdgcn_sched_barrier(0);
        asm volatile("s_waitcnt lgkmcnt(0)" ::: "memory");
        __builtin_amdgcn_s_barrier();
        __builtin_amdgcn_sched_barrier(0);
    }
}

// ---------------- K3: projection GEMM + BN stats (fp32, Plan A) -----
template <typename TOUT>
__global__ __launch_bounds__(256) void proj_kernel(
    const TOUT* __restrict__ out, const float* __restrict__ WpT4,
    const float* __restrict__ bp,
    float* __restrict__ proj, float* __restrict__ stats)
{
    __shared__ float outs[32][D2H];
    __shared__ float red[2][4];
    const int b0 = blockIdx.x * 32;
    const int l  = blockIdx.y;
    const int t  = threadIdx.x;
    for (int idx = t; idx < 32 * (D2H / 4); idx += 256) {
        int r = idx >> 6, c4 = idx & 63;
        float4 v = ld4(out + ((size_t)(b0 + r) * LL + l) * D2H + c4 * 4);
        *((float4*)&outs[r][c4 * 4]) = v;
    }
    __syncthreads();
    const int tr = t >> 5;
    const int tc = t & 31;
    float acc[4][4] = {};
    for (int k4 = 0; k4 < D2H / 4; ++k4) {
        float4 w[4];
        #pragma unroll
        for (int jj = 0; jj < 4; ++jj)
            w[jj] = ((const float4*)WpT4)[k4 * CDIM + tc * 4 + jj];
        #pragma unroll
        for (int i = 0; i < 4; ++i) {
            float4 a = *((const float4*)&outs[tr * 4 + i][k4 * 4]);
            #pragma unroll
            for (int jj = 0; jj < 4; ++jj) {
                acc[i][jj] = fmaf(a.x, w[jj].x, acc[i][jj]);
                acc[i][jj] = fmaf(a.y, w[jj].y, acc[i][jj]);
                acc[i][jj] = fmaf(a.z, w[jj].z, acc[i][jj]);
                acc[i][jj] = fmaf(a.w, w[jj].w, acc[i][jj]);
            }
        }
    }
    float s1 = 0.f, s2 = 0.f;
    #pragma unroll
    for (int i = 0; i < 4; ++i) {
        int b = b0 + tr * 4 + i;
        float4 pv;
        #pragma unroll
        for (int jj = 0; jj < 4; ++jj) {
            float v = acc[i][jj] + bp[tc * 4 + jj];
            (&pv.x)[jj] = v;
            s1 += v; s2 += v * v;
        }
        *((float4*)(proj + ((size_t)b * LL + l) * CDIM + tc * 4)) = pv;
    }
    #pragma unroll
    for (int off = 32; off > 0; off >>= 1) {
        s1 += __shfl_down(s1, off);
        s2 += __shfl_down(s2, off);
    }
    const int lane = t & 63, wv = t >> 6;
    if (lane == 0) { red[0][wv] = s1; red[1][wv] = s2; }
    __syncthreads();
    if (t == 0) {
        atomicAdd(&stats[l],      red[0][0] + red[0][1] + red[0][2] + red[0][3]);
        atomicAdd(&stats[LL + l], red[1][0] + red[1][1] + red[1][2] + red[1][3]);
    }
}

// ---------------- K3': projection via MFMA (bf16 out) + BN stats ----
__global__ __launch_bounds__(256) void proj_mfma_kernel(
    const unsigned short* __restrict__ out, const unsigned short* __restrict__ WpPk,
    const float* __restrict__ bp,
    float* __restrict__ proj, float* __restrict__ stats)
{
    __shared__ unsigned short outs[32][264];
    __shared__ float red[2][4];
    const int b0 = blockIdx.x * 32;
    const int l  = blockIdx.y;
    const int t  = threadIdx.x;
    const int w  = t >> 6, ln = t & 63;
    for (int idx = t; idx < 1024; idx += 256) {
        const int r = idx >> 5, c8 = idx & 31;
        *(short8v*)&outs[r][c8 * 8] =
            *(const short8v*)(out + ((size_t)(b0 + r) * LL + l) * D2H + c8 * 8);
    }
    __syncthreads();
    const int sa = ln & 15, ka = (ln >> 4) * 8;
    f32x4 acc00 = {0.f,0.f,0.f,0.f}, acc01 = {0.f,0.f,0.f,0.f};
    f32x4 acc10 = {0.f,0.f,0.f,0.f}, acc11 = {0.f,0.f,0.f,0.f};
    #pragma unroll
    for (int kt = 0; kt < 8; ++kt) {
        short8v a0 = *(const short8v*)&outs[sa][kt * 32 + ka];
        short8v a1 = *(const short8v*)&outs[16 + sa][kt * 32 + ka];
        const unsigned short* bbase = WpPk + ((size_t)kt * 8 + w * 2) * 512 + (size_t)ln * 8;
        short8v bh0 = *(const short8v*)(bbase);
        short8v bh1 = *(const short8v*)(bbase + 512);
        short8v bl0 = *(const short8v*)(bbase + 64 * 512);
        short8v bl1 = *(const short8v*)(bbase + 64 * 512 + 512);
        acc00 = __builtin_amdgcn_mfma_f32_16x16x32_bf16(a0, bh0, acc00, 0, 0, 0);
        acc00 = __builtin_amdgcn_mfma_f32_16x16x32_bf16(a0, bl0, acc00, 0, 0, 0);
        acc01 = __builtin_amdgcn_mfma_f32_16x16x32_bf16(a0, bh1, acc01, 0, 0, 0);
        acc01 = __builtin_amdgcn_mfma_f32_16x16x32_bf16(a0, bl1, acc01, 0, 0, 0);
        acc10 = __builtin_amdgcn_mfma_f32_16x16x32_bf16(a1, bh0, acc10, 0, 0, 0);
        acc10 = __builtin_amdgcn_mfma_f32_16x16x32_bf16(a1, bl0, acc10, 0, 0, 0);
        acc11 = __builtin_amdgcn_mfma_f32_16x16x32_bf16(a1, bh1, acc11, 0, 0, 0);
        acc11 = __builtin_amdgcn_mfma_f32_16x16x32_bf16(a1, bl1, acc11, 0, 0, 0);
    }
    float s1 = 0.f, s2 = 0.f;
    const int rb = (ln >> 4) * 4;
    const int cb = w * 32 + (ln & 15);
    #pragma unroll
    for (int mt = 0; mt < 2; ++mt) {
        #pragma unroll
        for (int n2 = 0; n2 < 2; ++n2) {
            const f32x4 a = mt == 0 ? (n2 == 0 ? acc00 : acc01)
                                    : (n2 == 0 ? acc10 : acc11);
            const int col = cb + n2 * 16;
            const float bpv = bp[col];
            #pragma unroll
            for (int reg = 0; reg < 4; ++reg) {
                const int row = b0 + mt * 16 + rb + reg;
                const float v = a[reg] + bpv;
                proj[((size_t)row * LL + l) * CDIM + col] = v;
                s1 += v; s2 += v * v;
            }
        }
    }
    #pragma unroll
    for (int off = 32; off > 0; off >>= 1) {
        s1 += __shfl_down(s1, off);
        s2 += __shfl_down(s2, off);
    }
    if (ln == 0) { red[0][w] = s1; red[1][w] = s2; }
    __syncthreads();
    if (t == 0) {
        atomicAdd(&stats[l],      red[0][0] + red[0][1] + red[0][2] + red[0][3]);
        atomicAdd(&stats[LL + l], red[1][0] + red[1][1] + red[1][2] + red[1][3]);
    }
}

// ---------------- K4: BN apply + relu + dot with ctx ----------------
__global__ __launch_bounds__(256) void logits_kernel(
    const float* __restrict__ proj, const float* __restrict__ stats,
    const float* __restrict__ gamma, const float* __restrict__ beta,
    const float* __restrict__ ctx, float* __restrict__ logits)
{
    const int idx  = blockIdx.x * 4 + (threadIdx.x >> 6);
    const int lane = threadIdx.x & 63;
    const int b = idx >> 6, l = idx & 63;
    const float invN = 1.f / (float)(BB * CDIM);
    const float mean = stats[l] * invN;
    const float var  = stats[LL + l] * invN - mean * mean;
    const float inv  = rsqrtf(var + EPSV);
    const float g = gamma[l], be = beta[l];
    const float2 p = ((const float2*)(proj + ((size_t)b * LL + l) * CDIM))[lane];
    const float2 c = ((const float2*)ctx)[lane];
    float v0 = fmaxf((p.x - mean) * inv * g + be, 0.f);
    float v1 = fmaxf((p.y - mean) * inv * g + be, 0.f);
    float s = v0 * c.x + v1 * c.y;
    #pragma unroll
    for (int off = 32; off > 0; off >>= 1) s += __shfl_down(s, off);
    if (lane == 0) logits[idx] = s;
}

// ---------------- K5: softmax over L + weighted sum -----------------
template <typename TOUT>
__global__ __launch_bounds__(256) void att_out_kernel(
    const TOUT* __restrict__ out, const float* __restrict__ logits,
    float* __restrict__ y)
{
    const int b = blockIdx.x;
    const int t = threadIdx.x;
    __shared__ float att[LL];
    if (t < 64) {
        float v = logits[b * LL + t];
        float m = v;
        #pragma unroll
        for (int off = 32; off > 0; off >>= 1) m = fmaxf(m, __shfl_xor(m, off));
        float e = __expf(v - m);
        float ssum = e;
        #pragma unroll
        for (int off = 32; off > 0; off >>= 1) ssum += __shfl_xor(ssum, off);
        att[t] = e / ssum;
    }
    __syncthreads();
    float acc = 0.f;
    const TOUT* ob = out + (size_t)b * LL * D2H + t;
    #pragma unroll
    for (int l = 0; l < LL; ++l) acc = fmaf(ldc(ob + (size_t)l * D2H), att[l], acc);
    y[b * D2H + t] = acc;
}

extern "C" void kernel_launch(void* const* d_in, const int* in_sizes, int n_in,
                              void* d_out, int out_size, void* d_ws, size_t ws_size,
                              hipStream_t stream) {
    const int*   xw     = (const int*)d_in[0];
    const int*   lens   = (const int*)d_in[2];
    const float* emb    = (const float*)d_in[3];
    const float* Wih_f  = (const float*)d_in[4];
    const float* Whh_f  = (const float*)d_in[5];
    const float* bih_f  = (const float*)d_in[6];
    const float* bhh_f  = (const float*)d_in[7];
    const float* Wih_b  = (const float*)d_in[8];
    const float* Whh_b  = (const float*)d_in[9];
    const float* bih_b  = (const float*)d_in[10];
    const float* bhh_b  = (const float*)d_in[11];
    const float* Wp     = (const float*)d_in[12];
    const float* bp     = (const float*)d_in[13];
    const float* gamma  = (const float*)d_in[14];
    const float* beta   = (const float*)d_in[15];
    const float* ctx    = (const float*)d_in[16];
    float* y = (float*)d_out;

    char* base = (char*)d_ws;
    size_t off = 0;
    auto alloc = [&](size_t bytes) -> void* {
        void* p = base + off; off += (bytes + 255) & ~(size_t)255; return p;
    };
    float* WpT4  = (float*)alloc((size_t)CDIM * D2H * 4);
    float* stats = (float*)alloc(2 * LL * 4);
    float* logit = (float*)alloc((size_t)BB * LL * 4);
    unsigned short* Wpk   = (unsigned short*)alloc((size_t)384 * 512 * 2);  // Whh frags
    unsigned short* WpPk  = (unsigned short*)alloc((size_t)128 * 512 * 2);  // Wp frags
    unsigned short* WihPk = (unsigned short*)alloc((size_t)672 * 512 * 2);  // Wih frags
    const size_t extras = off;
    const size_t peB_A  = (size_t)VV * PEW * 4;
    const size_t outB_A = (size_t)BB * LL * D2H * 4;
    const size_t needA  = extras + peB_A + outB_A + 4096;
    const bool planA = ws_size >= needA;

    zero_stats_kernel<<<1, 128, 0, stream>>>(stats);
    pack_whh_kernel<<<384, 64, 0, stream>>>(Whh_f, Whh_b, Wpk);

    if (planA) {
        transpose4_kernel<<<(CDIM * D2H / 4 + 255) / 256, 256, 0, stream>>>(Wp, WpT4, CDIM, D2H);
        float* PE   = (float*)alloc(peB_A);
        float* outb = (float*)alloc(outB_A);
        float* proj = (float*)PE;   // alias: PE dead after gru_kernel
        pe_kernel<float><<<dim3((VV + 127) / 128, PEW / 128), 256, 0, stream>>>(
            emb, Wih_f, bih_f, Wih_b, bih_b, PE);
        gru_kernel<float, float><<<256, 512, 0, stream>>>(
            xw, lens, PE, Wpk, bhh_f, bhh_b, outb);
        proj_kernel<float><<<dim3(BB / 32, LL), 256, 0, stream>>>(outb, WpT4, bp, proj, stats);
        logits_kernel<<<BB * LL / 4, 256, 0, stream>>>(proj, stats, gamma, beta, ctx, logit);
        att_out_kernel<float><<<BB, 256, 0, stream>>>(outb, logit, y);
    } else {
        pack_wp_kernel<<<128, 64, 0, stream>>>(Wp, WpPk);
        pack_wih_kernel<<<672, 64, 0, stream>>>(Wih_f, Wih_b, WihPk);
        unsigned short* PE   = (unsigned short*)alloc((size_t)VV * PEW * 2);
        unsigned short* outb = (unsigned short*)alloc((size_t)BB * LL * D2H * 2);
        float* proj = (float*)PE;   // alias: 67MB fp32 <= 76.8MB bf16 PE region
        pe_mfma_kernel<<<(VV + 31) / 32, 512, 0, stream>>>(
            emb, WihPk, bih_f, bih_b, PE);
        gru_kernel<unsigned short, unsigned short><<<256, 512, 0, stream>>>(
            xw, lens, PE, Wpk, bhh_f, bhh_b, outb);
        proj_mfma_kernel<<<dim3(BB / 32, LL), 256, 0, stream>>>(outb, WpPk, bp, proj, stats);
        logits_kernel<<<BB * LL / 4, 256, 0, stream>>>(proj, stats, gamma, beta, ctx, logit);
        att_out_kernel<unsigned short><<<BB, 256, 0, stream>>>(outb, logit, y);
    }
}

// Round 15
// 248.148 us; speedup vs baseline: 1.1021x; 1.0059x over previous
//
#include <hip/hip_runtime.h>
#include <math.h>

#define BB 2048
#define LL 64
#define EE 200
#define HH 128
#define CDIM 128
#define VV 50000
#define G3 384    // 3H
#define PEW 768   // 2*3H
#define D2H 256   // 2H
#define EPSV 1e-5f

typedef __attribute__((ext_vector_type(8))) short short8v;
typedef __attribute__((ext_vector_type(4))) float f32x4;

__device__ __forceinline__ float fast_sigmoid(float v) {
    return __builtin_amdgcn_rcpf(1.f + __expf(-v));
}
__device__ __forceinline__ float fast_tanh(float a) {
    float e = __expf(-2.f * fabsf(a));
    float m = (1.f - e) * __builtin_amdgcn_rcpf(1.f + e);
    return copysignf(m, a);
}

// ---- bf16 (raw ushort) <-> f32 helpers; storage-dtype overloads ----
__device__ __forceinline__ float bf2f(unsigned short u) {
    union { unsigned int i; float f; } c; c.i = ((unsigned int)u) << 16; return c.f;
}
__device__ __forceinline__ unsigned short f2bf(float f) {
    union { float f; unsigned int i; } c; c.f = f;
    unsigned int r = c.i + 0x7FFF + ((c.i >> 16) & 1);   // round-nearest-even
    return (unsigned short)(r >> 16);
}
__device__ __forceinline__ float ldc(const float* p) { return *p; }
__device__ __forceinline__ float ldc(const unsigned short* p) { return bf2f(*p); }
__device__ __forceinline__ void stc(float* p, float v) { *p = v; }
__device__ __forceinline__ void stc(unsigned short* p, float v) { *p = f2bf(v); }
__device__ __forceinline__ float4 ld4(const float* p) { return *(const float4*)p; }
__device__ __forceinline__ float4 ld4(const unsigned short* p) {
    ushort4 u = *(const ushort4*)p;
    return make_float4(bf2f(u.x), bf2f(u.y), bf2f(u.z), bf2f(u.w));
}

// ---------------- K0: zero the BN stats accumulators ----------------
__global__ void zero_stats_kernel(float* __restrict__ stats) {
    if (threadIdx.x < 2 * LL) stats[threadIdx.x] = 0.f;
}

// ---------------- K1: projected-embedding table (fp32, Plan A) ------
template <typename T>
__global__ __launch_bounds__(256) void pe_kernel(
    const float* __restrict__ emb,
    const float* __restrict__ Wih_f, const float* __restrict__ bih_f,
    const float* __restrict__ Wih_b, const float* __restrict__ bih_b,
    T* __restrict__ PE)
{
    __shared__ float As[8][136];
    __shared__ float Bs[8][136];
    const int mb = blockIdx.x * 128;
    const int nb = blockIdx.y * 128;
    const float* W  = (nb < G3) ? Wih_f : Wih_b;
    const float* bi = (nb < G3) ? bih_f : bih_b;
    const int nloc  = (nb < G3) ? nb : nb - G3;
    const int t  = threadIdx.x;
    const int tr = t >> 4, tc = t & 15;
    const int r  = t >> 1, q = t & 1;
    float acc[8][8] = {};
    for (int k0 = 0; k0 < EE; k0 += 8) {
        float4 av, bv;
        const int arow = mb + r;
        if (arow < VV) av = *(const float4*)(emb + (size_t)arow * EE + k0 + q * 4);
        else           av = make_float4(0.f, 0.f, 0.f, 0.f);
        bv = *(const float4*)(W + (size_t)(nloc + r) * EE + k0 + q * 4);
        __syncthreads();
        #pragma unroll
        for (int m = 0; m < 4; ++m) {
            As[q * 4 + m][r] = (&av.x)[m];
            Bs[q * 4 + m][r] = (&bv.x)[m];
        }
        __syncthreads();
        #pragma unroll
        for (int k = 0; k < 8; ++k) {
            float4 a0 = *(const float4*)&As[k][tr * 4];
            float4 a1 = *(const float4*)&As[k][64 + tr * 4];
            float4 b0 = *(const float4*)&Bs[k][tc * 4];
            float4 b1 = *(const float4*)&Bs[k][64 + tc * 4];
            float a8[8] = {a0.x,a0.y,a0.z,a0.w,a1.x,a1.y,a1.z,a1.w};
            float b8[8] = {b0.x,b0.y,b0.z,b0.w,b1.x,b1.y,b1.z,b1.w};
            #pragma unroll
            for (int i = 0; i < 8; ++i)
                #pragma unroll
                for (int j = 0; j < 8; ++j)
                    acc[i][j] = fmaf(a8[i], b8[j], acc[i][j]);
        }
    }
    #pragma unroll
    for (int i = 0; i < 8; ++i) {
        const int rl  = (i < 4) ? (tr * 4 + i) : (64 + tr * 4 + i - 4);
        const int row = mb + rl;
        if (row >= VV) continue;
        #pragma unroll
        for (int j = 0; j < 8; ++j) {
            const int cl = (j < 4) ? (tc * 4 + j) : (64 + tc * 4 + j - 4);
            stc(&PE[(size_t)row * PEW + nb + cl], acc[i][j] + bi[nloc + cl]);
        }
    }
}

// ---------------- K1b: k-major float4 repack of a [R][K] matrix -----
__global__ void transpose4_kernel(const float* __restrict__ src,
                                  float* __restrict__ dst, int R, int K) {
    int idx = blockIdx.x * blockDim.x + threadIdx.x;
    int total = R * (K >> 2);
    if (idx >= total) return;
    int k4 = idx / R, r = idx - k4 * R;
    float4 v;
    v.x = src[r * K + k4 * 4 + 0];
    v.y = src[r * K + k4 * 4 + 1];
    v.z = src[r * K + k4 * 4 + 2];
    v.w = src[r * K + k4 * 4 + 3];
    ((float4*)dst)[idx] = v;
}

// ---------------- K1c: pack Whh into MFMA B-fragments (bf16 hi only now used for p=0; keep hi/lo table) --
__global__ __launch_bounds__(64) void pack_whh_kernel(
    const float* __restrict__ Whh_f, const float* __restrict__ Whh_b,
    unsigned short* __restrict__ Wpk)
{
    const int fid = blockIdx.x;
    const int l   = threadIdx.x;
    const int g   = fid % 3;
    const int kt  = (fid / 3) & 3;
    const int p   = (fid / 12) & 1;
    const int w   = (fid / 24) & 7;
    const int dir = fid / 192;
    const float* W = dir ? Whh_b : Whh_f;
    const int n  = g * HH + w * 16 + (l & 15);
    const int k0 = kt * 32 + (l >> 4) * 8;
    unsigned short* dst = Wpk + (size_t)fid * 512 + l * 8;
    #pragma unroll
    for (int r = 0; r < 8; ++r) {
        float v = W[(size_t)n * HH + k0 + r];
        unsigned short hi = f2bf(v);
        dst[r] = p ? f2bf(v - bf2f(hi)) : hi;
    }
}

// ---------------- K1d: pack Wp into MFMA B-fragments (bf16 hi/lo) ---
__global__ __launch_bounds__(64) void pack_wp_kernel(
    const float* __restrict__ Wp, unsigned short* __restrict__ WpPk)
{
    const int fid = blockIdx.x;
    const int l   = threadIdx.x;
    const int nt  = fid & 7;
    const int kt  = (fid >> 3) & 7;
    const int p   = fid >> 6;
    const int n   = nt * 16 + (l & 15);
    const int k0  = kt * 32 + (l >> 4) * 8;
    unsigned short* dst = WpPk + (size_t)fid * 512 + l * 8;
    #pragma unroll
    for (int r = 0; r < 8; ++r) {
        float v = Wp[(size_t)n * D2H + k0 + r];
        unsigned short hi = f2bf(v);
        dst[r] = p ? f2bf(v - bf2f(hi)) : hi;
    }
}

// ---------------- K1e: pack Wih into MFMA B-fragments (bf16 hi/lo) --
__global__ __launch_bounds__(64) void pack_wih_kernel(
    const float* __restrict__ Wih_f, const float* __restrict__ Wih_b,
    unsigned short* __restrict__ WihPk)
{
    const int fid = blockIdx.x;
    const int l   = threadIdx.x;
    const int nt  = fid % 48;
    const int kt  = (fid / 48) % 7;
    const int p   = fid / 336;
    const int n   = nt * 16 + (l & 15);
    const int k0  = kt * 32 + (l >> 4) * 8;
    const float* W = (n < G3) ? Wih_f : Wih_b;
    const int nl   = (n < G3) ? n : n - G3;
    unsigned short* dst = WihPk + (size_t)fid * 512 + l * 8;
    #pragma unroll
    for (int r = 0; r < 8; ++r) {
        const int k = k0 + r;
        float v = (k < EE) ? W[(size_t)nl * EE + k] : 0.f;
        unsigned short hi = f2bf(v);
        dst[r] = p ? f2bf(v - bf2f(hi)) : hi;
    }
}

// ---------------- K1': PE table via MFMA (Plan C) -------------------
// r15: A-lo (emb lo) path dropped — 8 MFMA/kt (was 12), LDS halved to
// 16.9KB, staging lo-conversion gone. Error ~6.5e-4 sigma at preact
// (below PE's own bf16 storage rounding scale).
__global__ __launch_bounds__(512) void pe_mfma_kernel(
    const float* __restrict__ emb,
    const unsigned short* __restrict__ WihPk,
    const float* __restrict__ bih_f, const float* __restrict__ bih_b,
    unsigned short* __restrict__ PE)
{
    __shared__ unsigned short ahi[32][264];
    const int b0 = blockIdx.x * 32;
    const int t  = threadIdx.x;
    const int w  = t >> 6, ln = t & 63;     // 8 waves
    for (int idx = t; idx < 32 * 56; idx += 512) {
        const int r = idx / 56, q = idx - r * 56;
        const int row = b0 + r;
        float4 v = make_float4(0.f, 0.f, 0.f, 0.f);
        if (row < VV && q < 50)
            v = *(const float4*)(emb + (size_t)row * EE + q * 4);
        ushort4 h4;
        #pragma unroll
        for (int m = 0; m < 4; ++m)
            (&h4.x)[m] = f2bf((&v.x)[m]);
        *(ushort4*)&ahi[r][q * 4] = h4;
    }
    __syncthreads();
    const int sa = ln & 15, ka = (ln >> 4) * 8;
    const int rb = (ln >> 4) * 4;
    #pragma unroll
    for (int it = 0; it < 3; ++it) {
        const int ntb = it * 16 + w * 2;    // this wave's first n-tile (0..47)
        f32x4 acc00 = {0.f,0.f,0.f,0.f}, acc01 = {0.f,0.f,0.f,0.f};
        f32x4 acc10 = {0.f,0.f,0.f,0.f}, acc11 = {0.f,0.f,0.f,0.f};
        #pragma unroll
        for (int kt = 0; kt < 7; ++kt) {
            short8v ah0 = *(const short8v*)&ahi[sa][kt * 32 + ka];
            short8v ah1 = *(const short8v*)&ahi[16 + sa][kt * 32 + ka];
            const unsigned short* bb = WihPk + ((size_t)(kt * 48 + ntb)) * 512 + (size_t)ln * 8;
            short8v bh0 = *(const short8v*)(bb);
            short8v bh1 = *(const short8v*)(bb + 512);
            short8v bl0 = *(const short8v*)(bb + (size_t)336 * 512);
            short8v bl1 = *(const short8v*)(bb + (size_t)336 * 512 + 512);
            acc00 = __builtin_amdgcn_mfma_f32_16x16x32_bf16(ah0, bh0, acc00, 0, 0, 0);
            acc00 = __builtin_amdgcn_mfma_f32_16x16x32_bf16(ah0, bl0, acc00, 0, 0, 0);
            acc01 = __builtin_amdgcn_mfma_f32_16x16x32_bf16(ah0, bh1, acc01, 0, 0, 0);
            acc01 = __builtin_amdgcn_mfma_f32_16x16x32_bf16(ah0, bl1, acc01, 0, 0, 0);
            acc10 = __builtin_amdgcn_mfma_f32_16x16x32_bf16(ah1, bh0, acc10, 0, 0, 0);
            acc10 = __builtin_amdgcn_mfma_f32_16x16x32_bf16(ah1, bl0, acc10, 0, 0, 0);
            acc11 = __builtin_amdgcn_mfma_f32_16x16x32_bf16(ah1, bh1, acc11, 0, 0, 0);
            acc11 = __builtin_amdgcn_mfma_f32_16x16x32_bf16(ah1, bl1, acc11, 0, 0, 0);
        }
        #pragma unroll
        for (int n2 = 0; n2 < 2; ++n2) {
            const int col = (ntb + n2) * 16 + (ln & 15);
            const float bias = (col < G3) ? bih_f[col] : bih_b[col - G3];
            #pragma unroll
            for (int mt = 0; mt < 2; ++mt) {
                const f32x4 a = mt == 0 ? (n2 == 0 ? acc00 : acc01)
                                        : (n2 == 0 ? acc10 : acc11);
                #pragma unroll
                for (int reg = 0; reg < 4; ++reg) {
                    const int row = b0 + mt * 16 + rb + reg;
                    if (row < VV)
                        stc(&PE[(size_t)row * PEW + col], a[reg] + bias);
                }
            }
        }
    }
}

// ---------------- K2: bidirectional GRU recurrence (MFMA, pipelined) -
// r15: W-lo path dropped — 12 MFMA/step (was 24). Per-step preact error
// ~2e-4 (same class as the h-lo drop that measured zero absmax change).
template <typename TPE, typename TOUT>
__global__ __launch_bounds__(512, 2) void gru_kernel(
    const int* __restrict__ xw, const int* __restrict__ lens,
    const TPE* __restrict__ PE,
    const unsigned short* __restrict__ Wpk,
    const float* __restrict__ bhh_f, const float* __restrict__ bhh_b,
    TOUT* __restrict__ out)
{
    const int dir = blockIdx.x >> 7;
    const int b0  = (blockIdx.x & 127) * 16;
    const float* bhh = dir ? bhh_b : bhh_f;
    const int t = threadIdx.x;
    const int w = t >> 6;
    const int l = t & 63;
    const int j  = w * 16 + (l & 15);
    const int sb = (l >> 4) * 4;
    const int sa = l & 15;
    const int ka = (l >> 4) * 8;
    __shared__ unsigned short hh[2][16][136];

    short8v wb[4][3];   // hi-only fragments
    #pragma unroll
    for (int kt = 0; kt < 4; ++kt)
        #pragma unroll
        for (int g = 0; g < 3; ++g) {
            const size_t fid = (size_t)(dir * 192 + w * 24 + kt * 3 + g); // p=0
            wb[kt][g] = *(const short8v*)(Wpk + fid * 512 + (size_t)l * 8);
        }
    for (int i = t; i < 16 * 136; i += 512)
        ((unsigned short*)hh[0])[i] = 0;
    const float br  = bhh[j], bz = bhh[HH + j], bn_ = bhh[2 * HH + j];
    int lens_r[4];
    #pragma unroll
    for (int r = 0; r < 4; ++r) lens_r[r] = lens[b0 + sb + r];
    const int peBase = dir * G3;
    float hprev[4] = {0.f, 0.f, 0.f, 0.f};
    float xr[4], xz[4], xn[4];
    {
        const int lseq = dir ? (LL - 1) : 0;
        #pragma unroll
        for (int r = 0; r < 4; ++r) {
            const int tok = xw[(b0 + sb + r) * LL + lseq];
            const TPE* pp = PE + (size_t)tok * PEW + peBase + j;
            xr[r] = ldc(pp); xz[r] = ldc(pp + HH); xn[r] = ldc(pp + 2 * HH);
        }
    }
    __syncthreads();

    for (int step = 0; step < LL; ++step) {
        const int cur = step & 1, nxt = cur ^ 1;
        const int lseq = dir ? (LL - 1 - step) : step;
        short8v ah[4];
        #pragma unroll
        for (int kt = 0; kt < 4; ++kt)
            ah[kt] = *(const short8v*)&hh[cur][sa][kt * 32 + ka];
        // unconditional clamped prefetch of x(step+1)
        float xrn[4], xzn[4], xnn[4];
        {
            int lq = dir ? (LL - 2 - step) : (step + 1);
            lq = lq < 0 ? 0 : (lq > LL - 1 ? LL - 1 : lq);
            #pragma unroll
            for (int r = 0; r < 4; ++r) {
                const int tok = xw[(b0 + sb + r) * LL + lq];
                const TPE* pp = PE + (size_t)tok * PEW + peBase + j;
                xrn[r] = ldc(pp); xzn[r] = ldc(pp + HH); xnn[r] = ldc(pp + 2 * HH);
            }
        }
        f32x4 aR = {0.f,0.f,0.f,0.f}, aZ = {0.f,0.f,0.f,0.f}, aN = {0.f,0.f,0.f,0.f};
        #pragma unroll
        for (int kt = 0; kt < 4; ++kt) {
            aR = __builtin_amdgcn_mfma_f32_16x16x32_bf16(ah[kt], wb[kt][0], aR, 0, 0, 0);
            aZ = __builtin_amdgcn_mfma_f32_16x16x32_bf16(ah[kt], wb[kt][1], aZ, 0, 0, 0);
            aN = __builtin_amdgcn_mfma_f32_16x16x32_bf16(ah[kt], wb[kt][2], aN, 0, 0, 0);
        }
        #pragma unroll
        for (int r = 0; r < 4; ++r) {
            const int s = sb + r;
            const float rr = fast_sigmoid(xr[r] + aR[r] + br);
            const float zz = fast_sigmoid(xz[r] + aZ[r] + bz);
            const float nn = fast_tanh(xn[r] + rr * (aN[r] + bn_));
            const float h  = (1.f - zz) * nn + zz * hprev[r];
            hprev[r] = h;
            hh[nxt][s][j] = f2bf(h);
            stc(&out[((size_t)(b0 + s) * LL + lseq) * D2H + dir * HH + j],
                (lseq < lens_r[r]) ? h : 0.f);
        }
        #pragma unroll
        for (int r = 0; r < 4; ++r) {
            xr[r] = xrn[r]; xz[r] = xzn[r]; xn[r] = xnn[r];
        }
        // raw barrier: drain LDS ops only; stores/prefetch stay in flight
        __builtin_amdgcn_sched_barrier(0);
        asm volatile("s_waitcnt lgkmcnt(0)" ::: "memory");
        __builtin_amdgcn_s_barrier();
        __builtin_amdgcn_sched_barrier(0);
    }
}

// ---------------- K3: projection GEMM + BN stats (fp32, Plan A) -----
template <typename TOUT>
__global__ __launch_bounds__(256) void proj_kernel(
    const TOUT* __restrict__ out, const float* __restrict__ WpT4,
    const float* __restrict__ bp,
    float* __restrict__ proj, float* __restrict__ stats)
{
    __shared__ float outs[32][D2H];
    __shared__ float red[2][4];
    const int b0 = blockIdx.x * 32;
    const int l  = blockIdx.y;
    const int t  = threadIdx.x;
    for (int idx = t; idx < 32 * (D2H / 4); idx += 256) {
        int r = idx >> 6, c4 = idx & 63;
        float4 v = ld4(out + ((size_t)(b0 + r) * LL + l) * D2H + c4 * 4);
        *((float4*)&outs[r][c4 * 4]) = v;
    }
    __syncthreads();
    const int tr = t >> 5;
    const int tc = t & 31;
    float acc[4][4] = {};
    for (int k4 = 0; k4 < D2H / 4; ++k4) {
        float4 w[4];
        #pragma unroll
        for (int jj = 0; jj < 4; ++jj)
            w[jj] = ((const float4*)WpT4)[k4 * CDIM + tc * 4 + jj];
        #pragma unroll
        for (int i = 0; i < 4; ++i) {
            float4 a = *((const float4*)&outs[tr * 4 + i][k4 * 4]);
            #pragma unroll
            for (int jj = 0; jj < 4; ++jj) {
                acc[i][jj] = fmaf(a.x, w[jj].x, acc[i][jj]);
                acc[i][jj] = fmaf(a.y, w[jj].y, acc[i][jj]);
                acc[i][jj] = fmaf(a.z, w[jj].z, acc[i][jj]);
                acc[i][jj] = fmaf(a.w, w[jj].w, acc[i][jj]);
            }
        }
    }
    float s1 = 0.f, s2 = 0.f;
    #pragma unroll
    for (int i = 0; i < 4; ++i) {
        int b = b0 + tr * 4 + i;
        float4 pv;
        #pragma unroll
        for (int jj = 0; jj < 4; ++jj) {
            float v = acc[i][jj] + bp[tc * 4 + jj];
            (&pv.x)[jj] = v;
            s1 += v; s2 += v * v;
        }
        *((float4*)(proj + ((size_t)b * LL + l) * CDIM + tc * 4)) = pv;
    }
    #pragma unroll
    for (int off = 32; off > 0; off >>= 1) {
        s1 += __shfl_down(s1, off);
        s2 += __shfl_down(s2, off);
    }
    const int lane = t & 63, wv = t >> 6;
    if (lane == 0) { red[0][wv] = s1; red[1][wv] = s2; }
    __syncthreads();
    if (t == 0) {
        atomicAdd(&stats[l],      red[0][0] + red[0][1] + red[0][2] + red[0][3]);
        atomicAdd(&stats[LL + l], red[1][0] + red[1][1] + red[1][2] + red[1][3]);
    }
}

// ---------------- K3': projection via MFMA (bf16 out) + BN stats ----
__global__ __launch_bounds__(256) void proj_mfma_kernel(
    const unsigned short* __restrict__ out, const unsigned short* __restrict__ WpPk,
    const float* __restrict__ bp,
    float* __restrict__ proj, float* __restrict__ stats)
{
    __shared__ unsigned short outs[32][264];
    __shared__ float red[2][4];
    const int b0 = blockIdx.x * 32;
    const int l  = blockIdx.y;
    const int t  = threadIdx.x;
    const int w  = t >> 6, ln = t & 63;
    for (int idx = t; idx < 1024; idx += 256) {
        const int r = idx >> 5, c8 = idx & 31;
        *(short8v*)&outs[r][c8 * 8] =
            *(const short8v*)(out + ((size_t)(b0 + r) * LL + l) * D2H + c8 * 8);
    }
    __syncthreads();
    const int sa = ln & 15, ka = (ln >> 4) * 8;
    f32x4 acc00 = {0.f,0.f,0.f,0.f}, acc01 = {0.f,0.f,0.f,0.f};
    f32x4 acc10 = {0.f,0.f,0.f,0.f}, acc11 = {0.f,0.f,0.f,0.f};
    #pragma unroll
    for (int kt = 0; kt < 8; ++kt) {
        short8v a0 = *(const short8v*)&outs[sa][kt * 32 + ka];
        short8v a1 = *(const short8v*)&outs[16 + sa][kt * 32 + ka];
        const unsigned short* bbase = WpPk + ((size_t)kt * 8 + w * 2) * 512 + (size_t)ln * 8;
        short8v bh0 = *(const short8v*)(bbase);
        short8v bh1 = *(const short8v*)(bbase + 512);
        short8v bl0 = *(const short8v*)(bbase + 64 * 512);
        short8v bl1 = *(const short8v*)(bbase + 64 * 512 + 512);
        acc00 = __builtin_amdgcn_mfma_f32_16x16x32_bf16(a0, bh0, acc00, 0, 0, 0);
        acc00 = __builtin_amdgcn_mfma_f32_16x16x32_bf16(a0, bl0, acc00, 0, 0, 0);
        acc01 = __builtin_amdgcn_mfma_f32_16x16x32_bf16(a0, bh1, acc01, 0, 0, 0);
        acc01 = __builtin_amdgcn_mfma_f32_16x16x32_bf16(a0, bl1, acc01, 0, 0, 0);
        acc10 = __builtin_amdgcn_mfma_f32_16x16x32_bf16(a1, bh0, acc10, 0, 0, 0);
        acc10 = __builtin_amdgcn_mfma_f32_16x16x32_bf16(a1, bl0, acc10, 0, 0, 0);
        acc11 = __builtin_amdgcn_mfma_f32_16x16x32_bf16(a1, bh1, acc11, 0, 0, 0);
        acc11 = __builtin_amdgcn_mfma_f32_16x16x32_bf16(a1, bl1, acc11, 0, 0, 0);
    }
    float s1 = 0.f, s2 = 0.f;
    const int rb = (ln >> 4) * 4;
    const int cb = w * 32 + (ln & 15);
    #pragma unroll
    for (int mt = 0; mt < 2; ++mt) {
        #pragma unroll
        for (int n2 = 0; n2 < 2; ++n2) {
            const f32x4 a = mt == 0 ? (n2 == 0 ? acc00 : acc01)
                                    : (n2 == 0 ? acc10 : acc11);
            const int col = cb + n2 * 16;
            const float bpv = bp[col];
            #pragma unroll
            for (int reg = 0; reg < 4; ++reg) {
                const int row = b0 + mt * 16 + rb + reg;
                const float v = a[reg] + bpv;
                proj[((size_t)row * LL + l) * CDIM + col] = v;
                s1 += v; s2 += v * v;
            }
        }
    }
    #pragma unroll
    for (int off = 32; off > 0; off >>= 1) {
        s1 += __shfl_down(s1, off);
        s2 += __shfl_down(s2, off);
    }
    if (ln == 0) { red[0][w] = s1; red[1][w] = s2; }
    __syncthreads();
    if (t == 0) {
        atomicAdd(&stats[l],      red[0][0] + red[0][1] + red[0][2] + red[0][3]);
        atomicAdd(&stats[LL + l], red[1][0] + red[1][1] + red[1][2] + red[1][3]);
    }
}

// ---------------- K4: BN apply + relu + dot with ctx ----------------
__global__ __launch_bounds__(256) void logits_kernel(
    const float* __restrict__ proj, const float* __restrict__ stats,
    const float* __restrict__ gamma, const float* __restrict__ beta,
    const float* __restrict__ ctx, float* __restrict__ logits)
{
    const int idx  = blockIdx.x * 4 + (threadIdx.x >> 6);
    const int lane = threadIdx.x & 63;
    const int b = idx >> 6, l = idx & 63;
    const float invN = 1.f / (float)(BB * CDIM);
    const float mean = stats[l] * invN;
    const float var  = stats[LL + l] * invN - mean * mean;
    const float inv  = rsqrtf(var + EPSV);
    const float g = gamma[l], be = beta[l];
    const float2 p = ((const float2*)(proj + ((size_t)b * LL + l) * CDIM))[lane];
    const float2 c = ((const float2*)ctx)[lane];
    float v0 = fmaxf((p.x - mean) * inv * g + be, 0.f);
    float v1 = fmaxf((p.y - mean) * inv * g + be, 0.f);
    float s = v0 * c.x + v1 * c.y;
    #pragma unroll
    for (int off = 32; off > 0; off >>= 1) s += __shfl_down(s, off);
    if (lane == 0) logits[idx] = s;
}

// ---------------- K5: softmax over L + weighted sum -----------------
template <typename TOUT>
__global__ __launch_bounds__(256) void att_out_kernel(
    const TOUT* __restrict__ out, const float* __restrict__ logits,
    float* __restrict__ y)
{
    const int b = blockIdx.x;
    const int t = threadIdx.x;
    __shared__ float att[LL];
    if (t < 64) {
        float v = logits[b * LL + t];
        float m = v;
        #pragma unroll
        for (int off = 32; off > 0; off >>= 1) m = fmaxf(m, __shfl_xor(m, off));
        float e = __expf(v - m);
        float ssum = e;
        #pragma unroll
        for (int off = 32; off > 0; off >>= 1) ssum += __shfl_xor(ssum, off);
        att[t] = e / ssum;
    }
    __syncthreads();
    float acc = 0.f;
    const TOUT* ob = out + (size_t)b * LL * D2H + t;
    #pragma unroll
    for (int l = 0; l < LL; ++l) acc = fmaf(ldc(ob + (size_t)l * D2H), att[l], acc);
    y[b * D2H + t] = acc;
}

extern "C" void kernel_launch(void* const* d_in, const int* in_sizes, int n_in,
                              void* d_out, int out_size, void* d_ws, size_t ws_size,
                              hipStream_t stream) {
    const int*   xw     = (const int*)d_in[0];
    const int*   lens   = (const int*)d_in[2];
    const float* emb    = (const float*)d_in[3];
    const float* Wih_f  = (const float*)d_in[4];
    const float* Whh_f  = (const float*)d_in[5];
    const float* bih_f  = (const float*)d_in[6];
    const float* bhh_f  = (const float*)d_in[7];
    const float* Wih_b  = (const float*)d_in[8];
    const float* Whh_b  = (const float*)d_in[9];
    const float* bih_b  = (const float*)d_in[10];
    const float* bhh_b  = (const float*)d_in[11];
    const float* Wp     = (const float*)d_in[12];
    const float* bp     = (const float*)d_in[13];
    const float* gamma  = (const float*)d_in[14];
    const float* beta   = (const float*)d_in[15];
    const float* ctx    = (const float*)d_in[16];
    float* y = (float*)d_out;

    char* base = (char*)d_ws;
    size_t off = 0;
    auto alloc = [&](size_t bytes) -> void* {
        void* p = base + off; off += (bytes + 255) & ~(size_t)255; return p;
    };
    float* WpT4  = (float*)alloc((size_t)CDIM * D2H * 4);
    float* stats = (float*)alloc(2 * LL * 4);
    float* logit = (float*)alloc((size_t)BB * LL * 4);
    unsigned short* Wpk   = (unsigned short*)alloc((size_t)384 * 512 * 2);  // Whh frags
    unsigned short* WpPk  = (unsigned short*)alloc((size_t)128 * 512 * 2);  // Wp frags
    unsigned short* WihPk = (unsigned short*)alloc((size_t)672 * 512 * 2);  // Wih frags
    const size_t extras = off;
    const size_t peB_A  = (size_t)VV * PEW * 4;
    const size_t outB_A = (size_t)BB * LL * D2H * 4;
    const size_t needA  = extras + peB_A + outB_A + 4096;
    const bool planA = ws_size >= needA;

    zero_stats_kernel<<<1, 128, 0, stream>>>(stats);
    pack_whh_kernel<<<384, 64, 0, stream>>>(Whh_f, Whh_b, Wpk);

    if (planA) {
        transpose4_kernel<<<(CDIM * D2H / 4 + 255) / 256, 256, 0, stream>>>(Wp, WpT4, CDIM, D2H);
        float* PE   = (float*)alloc(peB_A);
        float* outb = (float*)alloc(outB_A);
        float* proj = (float*)PE;   // alias: PE dead after gru_kernel
        pe_kernel<float><<<dim3((VV + 127) / 128, PEW / 128), 256, 0, stream>>>(
            emb, Wih_f, bih_f, Wih_b, bih_b, PE);
        gru_kernel<float, float><<<256, 512, 0, stream>>>(
            xw, lens, PE, Wpk, bhh_f, bhh_b, outb);
        proj_kernel<float><<<dim3(BB / 32, LL), 256, 0, stream>>>(outb, WpT4, bp, proj, stats);
        logits_kernel<<<BB * LL / 4, 256, 0, stream>>>(proj, stats, gamma, beta, ctx, logit);
        att_out_kernel<float><<<BB, 256, 0, stream>>>(outb, logit, y);
    } else {
        pack_wp_kernel<<<128, 64, 0, stream>>>(Wp, WpPk);
        pack_wih_kernel<<<672, 64, 0, stream>>>(Wih_f, Wih_b, WihPk);
        unsigned short* PE   = (unsigned short*)alloc((size_t)VV * PEW * 2);
        unsigned short* outb = (unsigned short*)alloc((size_t)BB * LL * D2H * 2);
        float* proj = (float*)PE;   // alias: 67MB fp32 <= 76.8MB bf16 PE region
        pe_mfma_kernel<<<(VV + 31) / 32, 512, 0, stream>>>(
            emb, WihPk, bih_f, bih_b, PE);
        gru_kernel<unsigned short, unsigned short><<<256, 512, 0, stream>>>(
            xw, lens, PE, Wpk, bhh_f, bhh_b, outb);
        proj_mfma_kernel<<<dim3(BB / 32, LL), 256, 0, stream>>>(outb, WpPk, bp, proj, stats);
        logits_kernel<<<BB * LL / 4, 256, 0, stream>>>(proj, stats, gamma, beta, ctx, logit);
        att_out_kernel<unsigned short><<<BB, 256, 0, stream>>>(outb, logit, y);
    }
}

// Round 16
// 212.543 us; speedup vs baseline: 1.2867x; 1.1675x over previous
//
#include <hip/hip_runtime.h>
#include <math.h>

#define BB 2048
#define LL 64
#define EE 200
#define HH 128
#define CDIM 128
#define VV 50000
#define G3 384    // 3H
#define PEW 768   // 2*3H
#define D2H 256   // 2H
#define EPSV 1e-5f

typedef __attribute__((ext_vector_type(8))) short short8v;
typedef __attribute__((ext_vector_type(4))) float f32x4;

__device__ __forceinline__ float fast_sigmoid(float v) {
    return __builtin_amdgcn_rcpf(1.f + __expf(-v));
}
__device__ __forceinline__ float fast_tanh(float a) {
    float e = __expf(-2.f * fabsf(a));
    float m = (1.f - e) * __builtin_amdgcn_rcpf(1.f + e);
    return copysignf(m, a);
}

// ---- bf16 (raw ushort) <-> f32 helpers; storage-dtype overloads ----
__device__ __forceinline__ float bf2f(unsigned short u) {
    union { unsigned int i; float f; } c; c.i = ((unsigned int)u) << 16; return c.f;
}
__device__ __forceinline__ unsigned short f2bf(float f) {
    union { float f; unsigned int i; } c; c.f = f;
    unsigned int r = c.i + 0x7FFF + ((c.i >> 16) & 1);   // round-nearest-even
    return (unsigned short)(r >> 16);
}
__device__ __forceinline__ float ldc(const float* p) { return *p; }
__device__ __forceinline__ float ldc(const unsigned short* p) { return bf2f(*p); }
__device__ __forceinline__ void stc(float* p, float v) { *p = v; }
__device__ __forceinline__ void stc(unsigned short* p, float v) { *p = f2bf(v); }
__device__ __forceinline__ float4 ld4(const float* p) { return *(const float4*)p; }
__device__ __forceinline__ float4 ld4(const unsigned short* p) {
    ushort4 u = *(const ushort4*)p;
    return make_float4(bf2f(u.x), bf2f(u.y), bf2f(u.z), bf2f(u.w));
}

// ---------------- K0: zero the BN stats accumulators ----------------
__global__ void zero_stats_kernel(float* __restrict__ stats) {
    if (threadIdx.x < 2 * LL) stats[threadIdx.x] = 0.f;
}

// ---------------- K1: projected-embedding table (fp32, Plan A) ------
template <typename T>
__global__ __launch_bounds__(256) void pe_kernel(
    const float* __restrict__ emb,
    const float* __restrict__ Wih_f, const float* __restrict__ bih_f,
    const float* __restrict__ Wih_b, const float* __restrict__ bih_b,
    T* __restrict__ PE)
{
    __shared__ float As[8][136];
    __shared__ float Bs[8][136];
    const int mb = blockIdx.x * 128;
    const int nb = blockIdx.y * 128;
    const float* W  = (nb < G3) ? Wih_f : Wih_b;
    const float* bi = (nb < G3) ? bih_f : bih_b;
    const int nloc  = (nb < G3) ? nb : nb - G3;
    const int t  = threadIdx.x;
    const int tr = t >> 4, tc = t & 15;
    const int r  = t >> 1, q = t & 1;
    float acc[8][8] = {};
    for (int k0 = 0; k0 < EE; k0 += 8) {
        float4 av, bv;
        const int arow = mb + r;
        if (arow < VV) av = *(const float4*)(emb + (size_t)arow * EE + k0 + q * 4);
        else           av = make_float4(0.f, 0.f, 0.f, 0.f);
        bv = *(const float4*)(W + (size_t)(nloc + r) * EE + k0 + q * 4);
        __syncthreads();
        #pragma unroll
        for (int m = 0; m < 4; ++m) {
            As[q * 4 + m][r] = (&av.x)[m];
            Bs[q * 4 + m][r] = (&bv.x)[m];
        }
        __syncthreads();
        #pragma unroll
        for (int k = 0; k < 8; ++k) {
            float4 a0 = *(const float4*)&As[k][tr * 4];
            float4 a1 = *(const float4*)&As[k][64 + tr * 4];
            float4 b0 = *(const float4*)&Bs[k][tc * 4];
            float4 b1 = *(const float4*)&Bs[k][64 + tc * 4];
            float a8[8] = {a0.x,a0.y,a0.z,a0.w,a1.x,a1.y,a1.z,a1.w};
            float b8[8] = {b0.x,b0.y,b0.z,b0.w,b1.x,b1.y,b1.z,b1.w};
            #pragma unroll
            for (int i = 0; i < 8; ++i)
                #pragma unroll
                for (int j = 0; j < 8; ++j)
                    acc[i][j] = fmaf(a8[i], b8[j], acc[i][j]);
        }
    }
    #pragma unroll
    for (int i = 0; i < 8; ++i) {
        const int rl  = (i < 4) ? (tr * 4 + i) : (64 + tr * 4 + i - 4);
        const int row = mb + rl;
        if (row >= VV) continue;
        #pragma unroll
        for (int j = 0; j < 8; ++j) {
            const int cl = (j < 4) ? (tc * 4 + j) : (64 + tc * 4 + j - 4);
            stc(&PE[(size_t)row * PEW + nb + cl], acc[i][j] + bi[nloc + cl]);
        }
    }
}

// ---------------- K1b: k-major float4 repack of a [R][K] matrix -----
__global__ void transpose4_kernel(const float* __restrict__ src,
                                  float* __restrict__ dst, int R, int K) {
    int idx = blockIdx.x * blockDim.x + threadIdx.x;
    int total = R * (K >> 2);
    if (idx >= total) return;
    int k4 = idx / R, r = idx - k4 * R;
    float4 v;
    v.x = src[r * K + k4 * 4 + 0];
    v.y = src[r * K + k4 * 4 + 1];
    v.z = src[r * K + k4 * 4 + 2];
    v.w = src[r * K + k4 * 4 + 3];
    ((float4*)dst)[idx] = v;
}

// ---------------- K1c: pack Whh into MFMA B-fragments (bf16 hi/lo) --
__global__ __launch_bounds__(64) void pack_whh_kernel(
    const float* __restrict__ Whh_f, const float* __restrict__ Whh_b,
    unsigned short* __restrict__ Wpk)
{
    const int fid = blockIdx.x;
    const int l   = threadIdx.x;
    const int g   = fid % 3;
    const int kt  = (fid / 3) & 3;
    const int p   = (fid / 12) & 1;
    const int w   = (fid / 24) & 7;
    const int dir = fid / 192;
    const float* W = dir ? Whh_b : Whh_f;
    const int n  = g * HH + w * 16 + (l & 15);
    const int k0 = kt * 32 + (l >> 4) * 8;
    unsigned short* dst = Wpk + (size_t)fid * 512 + l * 8;
    #pragma unroll
    for (int r = 0; r < 8; ++r) {
        float v = W[(size_t)n * HH + k0 + r];
        unsigned short hi = f2bf(v);
        dst[r] = p ? f2bf(v - bf2f(hi)) : hi;
    }
}

// ---------------- K1d: pack Wp into MFMA B-fragments (bf16 hi/lo) ---
__global__ __launch_bounds__(64) void pack_wp_kernel(
    const float* __restrict__ Wp, unsigned short* __restrict__ WpPk)
{
    const int fid = blockIdx.x;
    const int l   = threadIdx.x;
    const int nt  = fid & 7;
    const int kt  = (fid >> 3) & 7;
    const int p   = fid >> 6;
    const int n   = nt * 16 + (l & 15);
    const int k0  = kt * 32 + (l >> 4) * 8;
    unsigned short* dst = WpPk + (size_t)fid * 512 + l * 8;
    #pragma unroll
    for (int r = 0; r < 8; ++r) {
        float v = Wp[(size_t)n * D2H + k0 + r];
        unsigned short hi = f2bf(v);
        dst[r] = p ? f2bf(v - bf2f(hi)) : hi;
    }
}

// ---------------- K1e: pack Wih into MFMA B-fragments (bf16 hi/lo) --
__global__ __launch_bounds__(64) void pack_wih_kernel(
    const float* __restrict__ Wih_f, const float* __restrict__ Wih_b,
    unsigned short* __restrict__ WihPk)
{
    const int fid = blockIdx.x;
    const int l   = threadIdx.x;
    const int nt  = fid % 48;
    const int kt  = (fid / 48) % 7;
    const int p   = fid / 336;
    const int n   = nt * 16 + (l & 15);
    const int k0  = kt * 32 + (l >> 4) * 8;
    const float* W = (n < G3) ? Wih_f : Wih_b;
    const int nl   = (n < G3) ? n : n - G3;
    unsigned short* dst = WihPk + (size_t)fid * 512 + l * 8;
    #pragma unroll
    for (int r = 0; r < 8; ++r) {
        const int k = k0 + r;
        float v = (k < EE) ? W[(size_t)nl * EE + k] : 0.f;
        unsigned short hi = f2bf(v);
        dst[r] = p ? f2bf(v - bf2f(hi)) : hi;
    }
}

// ---------------- K1': PE table via MFMA (Plan C) -------------------
// r16: M=64 rows/block (was 32). Each block reads the full 688KB WihPk
// table; doubling M halves that L2 traffic (1.08GB -> 0.54GB), which the
// r15 null (halve MFMA -> no change, all counters low) identified as the
// real bottleneck. Same arithmetic per output -> bit-identical results.
__global__ __launch_bounds__(512) void pe_mfma_kernel(
    const float* __restrict__ emb,
    const unsigned short* __restrict__ WihPk,
    const float* __restrict__ bih_f, const float* __restrict__ bih_b,
    unsigned short* __restrict__ PE)
{
    __shared__ unsigned short ahi[64][264];   // 33.8 KB
    const int b0 = blockIdx.x * 64;
    const int t  = threadIdx.x;
    const int w  = t >> 6, ln = t & 63;       // 8 waves
    for (int idx = t; idx < 64 * 56; idx += 512) {
        const int r = idx / 56, q = idx - r * 56;
        const int row = b0 + r;
        float4 v = make_float4(0.f, 0.f, 0.f, 0.f);
        if (row < VV && q < 50)
            v = *(const float4*)(emb + (size_t)row * EE + q * 4);
        ushort4 h4;
        #pragma unroll
        for (int m = 0; m < 4; ++m)
            (&h4.x)[m] = f2bf((&v.x)[m]);
        *(ushort4*)&ahi[r][q * 4] = h4;
    }
    __syncthreads();
    const int sa = ln & 15, ka = (ln >> 4) * 8;
    const int rb = (ln >> 4) * 4;
    #pragma unroll
    for (int it = 0; it < 3; ++it) {
        const int ntb = it * 16 + w * 2;      // this wave's first n-tile (0..47)
        f32x4 acc[4][2];
        #pragma unroll
        for (int mt = 0; mt < 4; ++mt)
            #pragma unroll
            for (int n2 = 0; n2 < 2; ++n2)
                acc[mt][n2] = (f32x4){0.f, 0.f, 0.f, 0.f};
        #pragma unroll
        for (int kt = 0; kt < 7; ++kt) {
            short8v ah[4];
            #pragma unroll
            for (int mt = 0; mt < 4; ++mt)
                ah[mt] = *(const short8v*)&ahi[mt * 16 + sa][kt * 32 + ka];
            const unsigned short* bb = WihPk + ((size_t)(kt * 48 + ntb)) * 512 + (size_t)ln * 8;
            short8v bh0 = *(const short8v*)(bb);
            short8v bh1 = *(const short8v*)(bb + 512);
            short8v bl0 = *(const short8v*)(bb + (size_t)336 * 512);
            short8v bl1 = *(const short8v*)(bb + (size_t)336 * 512 + 512);
            #pragma unroll
            for (int mt = 0; mt < 4; ++mt) {
                acc[mt][0] = __builtin_amdgcn_mfma_f32_16x16x32_bf16(ah[mt], bh0, acc[mt][0], 0, 0, 0);
                acc[mt][0] = __builtin_amdgcn_mfma_f32_16x16x32_bf16(ah[mt], bl0, acc[mt][0], 0, 0, 0);
                acc[mt][1] = __builtin_amdgcn_mfma_f32_16x16x32_bf16(ah[mt], bh1, acc[mt][1], 0, 0, 0);
                acc[mt][1] = __builtin_amdgcn_mfma_f32_16x16x32_bf16(ah[mt], bl1, acc[mt][1], 0, 0, 0);
            }
        }
        #pragma unroll
        for (int n2 = 0; n2 < 2; ++n2) {
            const int col = (ntb + n2) * 16 + (ln & 15);
            const float bias = (col < G3) ? bih_f[col] : bih_b[col - G3];
            #pragma unroll
            for (int mt = 0; mt < 4; ++mt) {
                #pragma unroll
                for (int reg = 0; reg < 4; ++reg) {
                    const int row = b0 + mt * 16 + rb + reg;
                    if (row < VV)
                        stc(&PE[(size_t)row * PEW + col], acc[mt][n2][reg] + bias);
                }
            }
        }
    }
}

// ---------------- K2: bidirectional GRU recurrence (MFMA, pipelined) -
template <typename TPE, typename TOUT>
__global__ __launch_bounds__(512, 2) void gru_kernel(
    const int* __restrict__ xw, const int* __restrict__ lens,
    const TPE* __restrict__ PE,
    const unsigned short* __restrict__ Wpk,
    const float* __restrict__ bhh_f, const float* __restrict__ bhh_b,
    TOUT* __restrict__ out)
{
    const int dir = blockIdx.x >> 7;
    const int b0  = (blockIdx.x & 127) * 16;
    const float* bhh = dir ? bhh_b : bhh_f;
    const int t = threadIdx.x;
    const int w = t >> 6;
    const int l = t & 63;
    const int j  = w * 16 + (l & 15);
    const int sb = (l >> 4) * 4;
    const int sa = l & 15;
    const int ka = (l >> 4) * 8;
    __shared__ unsigned short hh[2][16][136];

    short8v wb[4][3];   // hi-only fragments
    #pragma unroll
    for (int kt = 0; kt < 4; ++kt)
        #pragma unroll
        for (int g = 0; g < 3; ++g) {
            const size_t fid = (size_t)(dir * 192 + w * 24 + kt * 3 + g); // p=0
            wb[kt][g] = *(const short8v*)(Wpk + fid * 512 + (size_t)l * 8);
        }
    for (int i = t; i < 16 * 136; i += 512)
        ((unsigned short*)hh[0])[i] = 0;
    const float br  = bhh[j], bz = bhh[HH + j], bn_ = bhh[2 * HH + j];
    int lens_r[4];
    #pragma unroll
    for (int r = 0; r < 4; ++r) lens_r[r] = lens[b0 + sb + r];
    const int peBase = dir * G3;
    float hprev[4] = {0.f, 0.f, 0.f, 0.f};
    float xr[4], xz[4], xn[4];
    {
        const int lseq = dir ? (LL - 1) : 0;
        #pragma unroll
        for (int r = 0; r < 4; ++r) {
            const int tok = xw[(b0 + sb + r) * LL + lseq];
            const TPE* pp = PE + (size_t)tok * PEW + peBase + j;
            xr[r] = ldc(pp); xz[r] = ldc(pp + HH); xn[r] = ldc(pp + 2 * HH);
        }
    }
    __syncthreads();

    for (int step = 0; step < LL; ++step) {
        const int cur = step & 1, nxt = cur ^ 1;
        const int lseq = dir ? (LL - 1 - step) : step;
        short8v ah[4];
        #pragma unroll
        for (int kt = 0; kt < 4; ++kt)
            ah[kt] = *(const short8v*)&hh[cur][sa][kt * 32 + ka];
        // unconditional clamped prefetch of x(step+1)
        float xrn[4], xzn[4], xnn[4];
        {
            int lq = dir ? (LL - 2 - step) : (step + 1);
            lq = lq < 0 ? 0 : (lq > LL - 1 ? LL - 1 : lq);
            #pragma unroll
            for (int r = 0; r < 4; ++r) {
                const int tok = xw[(b0 + sb + r) * LL + lq];
                const TPE* pp = PE + (size_t)tok * PEW + peBase + j;
                xrn[r] = ldc(pp); xzn[r] = ldc(pp + HH); xnn[r] = ldc(pp + 2 * HH);
            }
        }
        f32x4 aR = {0.f,0.f,0.f,0.f}, aZ = {0.f,0.f,0.f,0.f}, aN = {0.f,0.f,0.f,0.f};
        #pragma unroll
        for (int kt = 0; kt < 4; ++kt) {
            aR = __builtin_amdgcn_mfma_f32_16x16x32_bf16(ah[kt], wb[kt][0], aR, 0, 0, 0);
            aZ = __builtin_amdgcn_mfma_f32_16x16x32_bf16(ah[kt], wb[kt][1], aZ, 0, 0, 0);
            aN = __builtin_amdgcn_mfma_f32_16x16x32_bf16(ah[kt], wb[kt][2], aN, 0, 0, 0);
        }
        #pragma unroll
        for (int r = 0; r < 4; ++r) {
            const int s = sb + r;
            const float rr = fast_sigmoid(xr[r] + aR[r] + br);
            const float zz = fast_sigmoid(xz[r] + aZ[r] + bz);
            const float nn = fast_tanh(xn[r] + rr * (aN[r] + bn_));
            const float h  = (1.f - zz) * nn + zz * hprev[r];
            hprev[r] = h;
            hh[nxt][s][j] = f2bf(h);
            stc(&out[((size_t)(b0 + s) * LL + lseq) * D2H + dir * HH + j],
                (lseq < lens_r[r]) ? h : 0.f);
        }
        #pragma unroll
        for (int r = 0; r < 4; ++r) {
            xr[r] = xrn[r]; xz[r] = xzn[r]; xn[r] = xnn[r];
        }
        // raw barrier: drain LDS ops only; stores/prefetch stay in flight
        __builtin_amdgcn_sched_barrier(0);
        asm volatile("s_waitcnt lgkmcnt(0)" ::: "memory");
        __builtin_amdgcn_s_barrier();
        __builtin_amdgcn_sched_barrier(0);
    }
}

// ---------------- K3: projection GEMM + BN stats (fp32, Plan A) -----
template <typename TOUT>
__global__ __launch_bounds__(256) void proj_kernel(
    const TOUT* __restrict__ out, const float* __restrict__ WpT4,
    const float* __restrict__ bp,
    float* __restrict__ proj, float* __restrict__ stats)
{
    __shared__ float outs[32][D2H];
    __shared__ float red[2][4];
    const int b0 = blockIdx.x * 32;
    const int l  = blockIdx.y;
    const int t  = threadIdx.x;
    for (int idx = t; idx < 32 * (D2H / 4); idx += 256) {
        int r = idx >> 6, c4 = idx & 63;
        float4 v = ld4(out + ((size_t)(b0 + r) * LL + l) * D2H + c4 * 4);
        *((float4*)&outs[r][c4 * 4]) = v;
    }
    __syncthreads();
    const int tr = t >> 5;
    const int tc = t & 31;
    float acc[4][4] = {};
    for (int k4 = 0; k4 < D2H / 4; ++k4) {
        float4 w[4];
        #pragma unroll
        for (int jj = 0; jj < 4; ++jj)
            w[jj] = ((const float4*)WpT4)[k4 * CDIM + tc * 4 + jj];
        #pragma unroll
        for (int i = 0; i < 4; ++i) {
            float4 a = *((const float4*)&outs[tr * 4 + i][k4 * 4]);
            #pragma unroll
            for (int jj = 0; jj < 4; ++jj) {
                acc[i][jj] = fmaf(a.x, w[jj].x, acc[i][jj]);
                acc[i][jj] = fmaf(a.y, w[jj].y, acc[i][jj]);
                acc[i][jj] = fmaf(a.z, w[jj].z, acc[i][jj]);
                acc[i][jj] = fmaf(a.w, w[jj].w, acc[i][jj]);
            }
        }
    }
    float s1 = 0.f, s2 = 0.f;
    #pragma unroll
    for (int i = 0; i < 4; ++i) {
        int b = b0 + tr * 4 + i;
        float4 pv;
        #pragma unroll
        for (int jj = 0; jj < 4; ++jj) {
            float v = acc[i][jj] + bp[tc * 4 + jj];
            (&pv.x)[jj] = v;
            s1 += v; s2 += v * v;
        }
        *((float4*)(proj + ((size_t)b * LL + l) * CDIM + tc * 4)) = pv;
    }
    #pragma unroll
    for (int off = 32; off > 0; off >>= 1) {
        s1 += __shfl_down(s1, off);
        s2 += __shfl_down(s2, off);
    }
    const int lane = t & 63, wv = t >> 6;
    if (lane == 0) { red[0][wv] = s1; red[1][wv] = s2; }
    __syncthreads();
    if (t == 0) {
        atomicAdd(&stats[l],      red[0][0] + red[0][1] + red[0][2] + red[0][3]);
        atomicAdd(&stats[LL + l], red[1][0] + red[1][1] + red[1][2] + red[1][3]);
    }
}

// ---------------- K3': projection via MFMA (bf16 out) + BN stats ----
// r16: M=64 rows/block, 8 waves x 1 n-tile each (was 32 rows, 4 waves x 2).
// Halves+quarters the per-block WpPk L2 re-read (1.07GB -> 0.27GB total).
__global__ __launch_bounds__(512) void proj_mfma_kernel(
    const unsigned short* __restrict__ out, const unsigned short* __restrict__ WpPk,
    const float* __restrict__ bp,
    float* __restrict__ proj, float* __restrict__ stats)
{
    __shared__ unsigned short outs[64][264];   // 33.8 KB
    __shared__ float red[2][8];
    const int b0 = blockIdx.x * 64;
    const int l  = blockIdx.y;
    const int t  = threadIdx.x;
    const int w  = t >> 6, ln = t & 63;        // 8 waves, wave w owns n-tile w
    for (int idx = t; idx < 64 * 32; idx += 512) {
        const int r = idx >> 5, c8 = idx & 31;
        *(short8v*)&outs[r][c8 * 8] =
            *(const short8v*)(out + ((size_t)(b0 + r) * LL + l) * D2H + c8 * 8);
    }
    __syncthreads();
    const int sa = ln & 15, ka = (ln >> 4) * 8;
    f32x4 acc[4];
    #pragma unroll
    for (int mt = 0; mt < 4; ++mt) acc[mt] = (f32x4){0.f, 0.f, 0.f, 0.f};
    #pragma unroll
    for (int kt = 0; kt < 8; ++kt) {
        short8v a[4];
        #pragma unroll
        for (int mt = 0; mt < 4; ++mt)
            a[mt] = *(const short8v*)&outs[mt * 16 + sa][kt * 32 + ka];
        const unsigned short* bbase = WpPk + ((size_t)kt * 8 + w) * 512 + (size_t)ln * 8;
        short8v bh = *(const short8v*)(bbase);
        short8v bl = *(const short8v*)(bbase + 64 * 512);
        #pragma unroll
        for (int mt = 0; mt < 4; ++mt) {
            acc[mt] = __builtin_amdgcn_mfma_f32_16x16x32_bf16(a[mt], bh, acc[mt], 0, 0, 0);
            acc[mt] = __builtin_amdgcn_mfma_f32_16x16x32_bf16(a[mt], bl, acc[mt], 0, 0, 0);
        }
    }
    float s1 = 0.f, s2 = 0.f;
    const int rb = (ln >> 4) * 4;
    const int col = w * 16 + (ln & 15);
    const float bpv = bp[col];
    #pragma unroll
    for (int mt = 0; mt < 4; ++mt) {
        #pragma unroll
        for (int reg = 0; reg < 4; ++reg) {
            const int row = b0 + mt * 16 + rb + reg;
            const float v = acc[mt][reg] + bpv;
            proj[((size_t)row * LL + l) * CDIM + col] = v;
            s1 += v; s2 += v * v;
        }
    }
    #pragma unroll
    for (int off = 32; off > 0; off >>= 1) {
        s1 += __shfl_down(s1, off);
        s2 += __shfl_down(s2, off);
    }
    if (ln == 0) { red[0][w] = s1; red[1][w] = s2; }
    __syncthreads();
    if (t == 0) {
        float r1 = 0.f, r2 = 0.f;
        #pragma unroll
        for (int i = 0; i < 8; ++i) { r1 += red[0][i]; r2 += red[1][i]; }
        atomicAdd(&stats[l], r1);
        atomicAdd(&stats[LL + l], r2);
    }
}

// ---------------- K4: BN apply + relu + dot with ctx ----------------
__global__ __launch_bounds__(256) void logits_kernel(
    const float* __restrict__ proj, const float* __restrict__ stats,
    const float* __restrict__ gamma, const float* __restrict__ beta,
    const float* __restrict__ ctx, float* __restrict__ logits)
{
    const int idx  = blockIdx.x * 4 + (threadIdx.x >> 6);
    const int lane = threadIdx.x & 63;
    const int b = idx >> 6, l = idx & 63;
    const float invN = 1.f / (float)(BB * CDIM);
    const float mean = stats[l] * invN;
    const float var  = stats[LL + l] * invN - mean * mean;
    const float inv  = rsqrtf(var + EPSV);
    const float g = gamma[l], be = beta[l];
    const float2 p = ((const float2*)(proj + ((size_t)b * LL + l) * CDIM))[lane];
    const float2 c = ((const float2*)ctx)[lane];
    float v0 = fmaxf((p.x - mean) * inv * g + be, 0.f);
    float v1 = fmaxf((p.y - mean) * inv * g + be, 0.f);
    float s = v0 * c.x + v1 * c.y;
    #pragma unroll
    for (int off = 32; off > 0; off >>= 1) s += __shfl_down(s, off);
    if (lane == 0) logits[idx] = s;
}

// ---------------- K5: softmax over L + weighted sum -----------------
template <typename TOUT>
__global__ __launch_bounds__(256) void att_out_kernel(
    const TOUT* __restrict__ out, const float* __restrict__ logits,
    float* __restrict__ y)
{
    const int b = blockIdx.x;
    const int t = threadIdx.x;
    __shared__ float att[LL];
    if (t < 64) {
        float v = logits[b * LL + t];
        float m = v;
        #pragma unroll
        for (int off = 32; off > 0; off >>= 1) m = fmaxf(m, __shfl_xor(m, off));
        float e = __expf(v - m);
        float ssum = e;
        #pragma unroll
        for (int off = 32; off > 0; off >>= 1) ssum += __shfl_xor(ssum, off);
        att[t] = e / ssum;
    }
    __syncthreads();
    float acc = 0.f;
    const TOUT* ob = out + (size_t)b * LL * D2H + t;
    #pragma unroll
    for (int l = 0; l < LL; ++l) acc = fmaf(ldc(ob + (size_t)l * D2H), att[l], acc);
    y[b * D2H + t] = acc;
}

extern "C" void kernel_launch(void* const* d_in, const int* in_sizes, int n_in,
                              void* d_out, int out_size, void* d_ws, size_t ws_size,
                              hipStream_t stream) {
    const int*   xw     = (const int*)d_in[0];
    const int*   lens   = (const int*)d_in[2];
    const float* emb    = (const float*)d_in[3];
    const float* Wih_f  = (const float*)d_in[4];
    const float* Whh_f  = (const float*)d_in[5];
    const float* bih_f  = (const float*)d_in[6];
    const float* bhh_f  = (const float*)d_in[7];
    const float* Wih_b  = (const float*)d_in[8];
    const float* Whh_b  = (const float*)d_in[9];
    const float* bih_b  = (const float*)d_in[10];
    const float* bhh_b  = (const float*)d_in[11];
    const float* Wp     = (const float*)d_in[12];
    const float* bp     = (const float*)d_in[13];
    const float* gamma  = (const float*)d_in[14];
    const float* beta   = (const float*)d_in[15];
    const float* ctx    = (const float*)d_in[16];
    float* y = (float*)d_out;

    char* base = (char*)d_ws;
    size_t off = 0;
    auto alloc = [&](size_t bytes) -> void* {
        void* p = base + off; off += (bytes + 255) & ~(size_t)255; return p;
    };
    float* WpT4  = (float*)alloc((size_t)CDIM * D2H * 4);
    float* stats = (float*)alloc(2 * LL * 4);
    float* logit = (float*)alloc((size_t)BB * LL * 4);
    unsigned short* Wpk   = (unsigned short*)alloc((size_t)384 * 512 * 2);  // Whh frags
    unsigned short* WpPk  = (unsigned short*)alloc((size_t)128 * 512 * 2);  // Wp frags
    unsigned short* WihPk = (unsigned short*)alloc((size_t)672 * 512 * 2);  // Wih frags
    const size_t extras = off;
    const size_t peB_A  = (size_t)VV * PEW * 4;
    const size_t outB_A = (size_t)BB * LL * D2H * 4;
    const size_t needA  = extras + peB_A + outB_A + 4096;
    const bool planA = ws_size >= needA;

    zero_stats_kernel<<<1, 128, 0, stream>>>(stats);
    pack_whh_kernel<<<384, 64, 0, stream>>>(Whh_f, Whh_b, Wpk);

    if (planA) {
        transpose4_kernel<<<(CDIM * D2H / 4 + 255) / 256, 256, 0, stream>>>(Wp, WpT4, CDIM, D2H);
        float* PE   = (float*)alloc(peB_A);
        float* outb = (float*)alloc(outB_A);
        float* proj = (float*)PE;   // alias: PE dead after gru_kernel
        pe_kernel<float><<<dim3((VV + 127) / 128, PEW / 128), 256, 0, stream>>>(
            emb, Wih_f, bih_f, Wih_b, bih_b, PE);
        gru_kernel<float, float><<<256, 512, 0, stream>>>(
            xw, lens, PE, Wpk, bhh_f, bhh_b, outb);
        proj_kernel<float><<<dim3(BB / 32, LL), 256, 0, stream>>>(outb, WpT4, bp, proj, stats);
        logits_kernel<<<BB * LL / 4, 256, 0, stream>>>(proj, stats, gamma, beta, ctx, logit);
        att_out_kernel<float><<<BB, 256, 0, stream>>>(outb, logit, y);
    } else {
        pack_wp_kernel<<<128, 64, 0, stream>>>(Wp, WpPk);
        pack_wih_kernel<<<672, 64, 0, stream>>>(Wih_f, Wih_b, WihPk);
        unsigned short* PE   = (unsigned short*)alloc((size_t)VV * PEW * 2);
        unsigned short* outb = (unsigned short*)alloc((size_t)BB * LL * D2H * 2);
        float* proj = (float*)PE;   // alias: 67MB fp32 <= 76.8MB bf16 PE region
        pe_mfma_kernel<<<(VV + 63) / 64, 512, 0, stream>>>(
            emb, WihPk, bih_f, bih_b, PE);
        gru_kernel<unsigned short, unsigned short><<<256, 512, 0, stream>>>(
            xw, lens, PE, Wpk, bhh_f, bhh_b, outb);
        proj_mfma_kernel<<<dim3(BB / 64, LL), 512, 0, stream>>>(outb, WpPk, bp, proj, stats);
        logits_kernel<<<BB * LL / 4, 256, 0, stream>>>(proj, stats, gamma, beta, ctx, logit);
        att_out_kernel<unsigned short><<<BB, 256, 0, stream>>>(outb, logit, y);
    }
}